// Round 1
// baseline (679.812 us; speedup 1.0000x reference)
//
#include <hip/hip_runtime.h>
#include <hip/hip_bf16.h>

typedef __bf16 bf16;
typedef bf16 bf16x8 __attribute__((ext_vector_type(8)));
typedef bf16 bf16x4 __attribute__((ext_vector_type(4)));
typedef float f32x4 __attribute__((ext_vector_type(4)));

#define NB 8
#define QLEN 512
#define KVL 4096
#define DIM 768
#define NH 12
#define HD 64

// ---------------- LayerNorm(query) -> bf16 ----------------
__global__ __launch_bounds__(256) void ln_q(const float* __restrict__ x,
    const float* __restrict__ g, const float* __restrict__ beta,
    bf16* __restrict__ out)
{
  int row  = blockIdx.x * 4 + (threadIdx.x >> 6);
  int lane = threadIdx.x & 63;
  const float* rp = x + (size_t)row * DIM;
  f32x4 v[3];
  float s = 0.f, s2 = 0.f;
#pragma unroll
  for (int i = 0; i < 3; ++i) {
    v[i] = *reinterpret_cast<const f32x4*>(rp + (i * 64 + lane) * 4);
#pragma unroll
    for (int j = 0; j < 4; ++j) { s += v[i][j]; s2 += v[i][j] * v[i][j]; }
  }
#pragma unroll
  for (int o = 1; o < 64; o <<= 1) { s += __shfl_xor(s, o); s2 += __shfl_xor(s2, o); }
  float mean = s * (1.f / 768.f);
  float var  = s2 * (1.f / 768.f) - mean * mean;
  float rstd = rsqrtf(var + 1e-5f);
#pragma unroll
  for (int i = 0; i < 3; ++i) {
    int c = (i * 64 + lane) * 4;
    f32x4 gg = *reinterpret_cast<const f32x4*>(g + c);
    f32x4 bb = *reinterpret_cast<const f32x4*>(beta + c);
    bf16x4 o4;
#pragma unroll
    for (int j = 0; j < 4; ++j) o4[j] = (bf16)((v[i][j] - mean) * rstd * gg[j] + bb[j]);
    *reinterpret_cast<bf16x4*>(out + (size_t)row * DIM + c) = o4;
  }
}

// ---------------- mask int32 -> bitmask (bit=1 means masked out) ----------------
__global__ __launch_bounds__(256) void pack_mask(const int* __restrict__ m,
                                                 unsigned* __restrict__ bits)
{
  const int total = NB * QLEN * KVL;
  int stride = gridDim.x * blockDim.x;
  for (int i = blockIdx.x * blockDim.x + threadIdx.x; i < total; i += stride) {
    unsigned long long bal = __ballot(m[i] == 1);
    int lane = threadIdx.x & 63;
    if ((lane & 31) == 0)
      bits[i >> 5] = (unsigned)(bal >> (lane & 32));
  }
}

// ---------------- GEMM: Out[M,768] = A[M,768] @ W[768,768]^T + bias ----------------
// tile 128x64, BK=64, 256 threads (4 waves, 2x2 over MxN), mfma 16x16x32 bf16
template<bool A_IS_BF16, bool OUT_BF16>
__global__ __launch_bounds__(256) void gemm_bt(const void* __restrict__ Aptr,
    const float* __restrict__ W, const float* __restrict__ bias,
    void* __restrict__ Out)
{
  const int K = 768, N = 768;
  __shared__ __align__(16) bf16 a_s[128][72];
  __shared__ __align__(16) bf16 b_s[64][72];
  int id = blockIdx.x;
  int nt = id % (N / 64), mt = id / (N / 64);
  int m0 = mt * 128, n0 = nt * 64;
  int tid = threadIdx.x;
  int lane = tid & 63, wid = tid >> 6;
  int l16 = lane & 15, g4 = lane >> 4;
  int wm = wid >> 1, wn = wid & 1;
  f32x4 acc[4][2] = {};

  for (int k0 = 0; k0 < K; k0 += 64) {
    // stage A tile: 128x64 -> 1024 octets, 4 per thread
#pragma unroll
    for (int i = 0; i < 4; ++i) {
      int oct = tid + i * 256;
      int row = oct >> 3, col = (oct & 7) * 8;
      bf16x8 v;
      if constexpr (A_IS_BF16) {
        v = *reinterpret_cast<const bf16x8*>((const bf16*)Aptr + (size_t)(m0 + row) * K + k0 + col);
      } else {
        const float* ap = (const float*)Aptr + (size_t)(m0 + row) * K + k0 + col;
        f32x4 f0 = *reinterpret_cast<const f32x4*>(ap);
        f32x4 f1 = *reinterpret_cast<const f32x4*>(ap + 4);
#pragma unroll
        for (int j = 0; j < 4; ++j) { v[j] = (bf16)f0[j]; v[4 + j] = (bf16)f1[j]; }
      }
      *reinterpret_cast<bf16x8*>(&a_s[row][col]) = v;
    }
    // stage B tile (W rows are the N dim): 64x64 -> 512 octets, 2 per thread
#pragma unroll
    for (int i = 0; i < 2; ++i) {
      int oct = tid + i * 256;
      int row = oct >> 3, col = (oct & 7) * 8;
      const float* wp = W + (size_t)(n0 + row) * K + k0 + col;
      f32x4 f0 = *reinterpret_cast<const f32x4*>(wp);
      f32x4 f1 = *reinterpret_cast<const f32x4*>(wp + 4);
      bf16x8 v;
#pragma unroll
      for (int j = 0; j < 4; ++j) { v[j] = (bf16)f0[j]; v[4 + j] = (bf16)f1[j]; }
      *reinterpret_cast<bf16x8*>(&b_s[row][col]) = v;
    }
    __syncthreads();
#pragma unroll
    for (int kk = 0; kk < 2; ++kk) {
      bf16x8 af[4], bfr[2];
#pragma unroll
      for (int mi = 0; mi < 4; ++mi)
        af[mi] = *reinterpret_cast<const bf16x8*>(&a_s[wm * 64 + mi * 16 + l16][kk * 32 + g4 * 8]);
#pragma unroll
      for (int ni = 0; ni < 2; ++ni)
        bfr[ni] = *reinterpret_cast<const bf16x8*>(&b_s[wn * 32 + ni * 16 + l16][kk * 32 + g4 * 8]);
#pragma unroll
      for (int mi = 0; mi < 4; ++mi)
#pragma unroll
        for (int ni = 0; ni < 2; ++ni)
          acc[mi][ni] = __builtin_amdgcn_mfma_f32_16x16x32_bf16(af[mi], bfr[ni], acc[mi][ni], 0, 0, 0);
    }
    __syncthreads();
  }
  // epilogue: C frag layout col = lane&15, row = (lane>>4)*4 + j
#pragma unroll
  for (int mi = 0; mi < 4; ++mi)
#pragma unroll
    for (int ni = 0; ni < 2; ++ni) {
      int col = n0 + wn * 32 + ni * 16 + l16;
      float bv = bias[col];
#pragma unroll
      for (int j = 0; j < 4; ++j) {
        int row = m0 + wm * 64 + mi * 16 + g4 * 4 + j;
        float v = acc[mi][ni][j] + bv;
        if constexpr (OUT_BF16) ((bf16*)Out)[(size_t)row * N + col] = (bf16)v;
        else                    ((float*)Out)[(size_t)row * N + col] = v;
      }
    }
}

// ---------------- fused masked flash attention ----------------
// grid (h=12, qtile=8, b=8), 256 threads = 4 waves, each wave owns 16 q rows.
// KV tiles of 32; K staged row-major in LDS, V staged transposed.
__global__ __launch_bounds__(256) void attn(const bf16* __restrict__ Qp,
    const bf16* __restrict__ Kp, const bf16* __restrict__ Vp,
    const unsigned* __restrict__ mbits, bf16* __restrict__ Ctx)
{
  int h = blockIdx.x, qt = blockIdx.y, b = blockIdx.z;
  int tid = threadIdx.x, lane = tid & 63, wid = tid >> 6;
  int g4 = lane >> 4, l16 = lane & 15;
  __shared__ __align__(16) bf16 k_s[32][72];
  __shared__ __align__(16) bf16 v_s[64][40];
  __shared__ __align__(16) bf16 p_s[4][16][40];

  int qrow_w = b * QLEN + qt * 64 + wid * 16;  // wave's first q row (absolute)

  bf16x8 qf[2];
#pragma unroll
  for (int kk = 0; kk < 2; ++kk)
    qf[kk] = *reinterpret_cast<const bf16x8*>(Qp + (size_t)(qrow_w + l16) * DIM + h * HD + kk * 32 + g4 * 8);

  f32x4 oacc[4] = {};
  float m_r[4], l_r[4];
#pragma unroll
  for (int j = 0; j < 4; ++j) { m_r[j] = -1e30f; l_r[j] = 0.f; }

  const bf16* Kb = Kp + (size_t)b * KVL * DIM + h * HD;
  const bf16* Vb = Vp + (size_t)b * KVL * DIM + h * HD;

  for (int kv0 = 0; kv0 < KVL; kv0 += 32) {
    // stage K tile 32x64
    {
      int row = tid >> 3, col = (tid & 7) * 8;
      *reinterpret_cast<bf16x8*>(&k_s[row][col]) =
          *reinterpret_cast<const bf16x8*>(Kb + (size_t)(kv0 + row) * DIM + col);
    }
    // stage V tile transposed: v_s[d][kv]
    {
      int kv = tid & 31, d0 = (tid >> 5) * 8;
      bf16x8 v = *reinterpret_cast<const bf16x8*>(Vb + (size_t)(kv0 + kv) * DIM + d0);
#pragma unroll
      for (int j = 0; j < 8; ++j) v_s[d0 + j][kv] = v[j];
    }
    __syncthreads();

    // S = Q K^T  (two 16-col blocks)
    f32x4 sacc[2] = {};
#pragma unroll
    for (int nb = 0; nb < 2; ++nb)
#pragma unroll
      for (int kk = 0; kk < 2; ++kk) {
        bf16x8 kf = *reinterpret_cast<const bf16x8*>(&k_s[nb * 16 + l16][kk * 32 + g4 * 8]);
        sacc[nb] = __builtin_amdgcn_mfma_f32_16x16x32_bf16(qf[kk], kf, sacc[nb], 0, 0, 0);
      }

    // mask + online softmax (rows j, 16-lane-group reduce over kv)
    float p[2][4], corr[4];
#pragma unroll
    for (int j = 0; j < 4; ++j) {
      int qabs = qrow_w + g4 * 4 + j;
      unsigned w = mbits[(size_t)qabs * (KVL / 32) + (kv0 >> 5)];
      float s0 = ((w >> l16) & 1u) ? -1e30f : sacc[0][j] * 0.125f;
      float s1 = ((w >> (16 + l16)) & 1u) ? -1e30f : sacc[1][j] * 0.125f;
      float tm = fmaxf(s0, s1);
#pragma unroll
      for (int o = 1; o < 16; o <<= 1) tm = fmaxf(tm, __shfl_xor(tm, o));
      float mnew = fmaxf(m_r[j], tm);
      corr[j] = __expf(m_r[j] - mnew);
      m_r[j] = mnew;
      float p0 = __expf(s0 - mnew);
      float p1 = __expf(s1 - mnew);
      p[0][j] = p0; p[1][j] = p1;
      float ts = p0 + p1;
#pragma unroll
      for (int o = 1; o < 16; o <<= 1) ts += __shfl_xor(ts, o);
      l_r[j] = l_r[j] * corr[j] + ts;
    }

    // P -> per-wave LDS (C-frag layout -> A-frag layout)
#pragma unroll
    for (int nb = 0; nb < 2; ++nb)
#pragma unroll
      for (int j = 0; j < 4; ++j)
        p_s[wid][g4 * 4 + j][nb * 16 + l16] = (bf16)p[nb][j];

    // rescale O accumulators
#pragma unroll
    for (int db = 0; db < 4; ++db)
#pragma unroll
      for (int j = 0; j < 4; ++j) oacc[db][j] *= corr[j];

    // O += P V
    bf16x8 pf = *reinterpret_cast<const bf16x8*>(&p_s[wid][l16][g4 * 8]);
#pragma unroll
    for (int db = 0; db < 4; ++db) {
      bf16x8 vf = *reinterpret_cast<const bf16x8*>(&v_s[db * 16 + l16][g4 * 8]);
      oacc[db] = __builtin_amdgcn_mfma_f32_16x16x32_bf16(pf, vf, oacc[db], 0, 0, 0);
    }
    __syncthreads();
  }

  // epilogue: Ctx[q][h*64 + d] = O / l
#pragma unroll
  for (int db = 0; db < 4; ++db)
#pragma unroll
    for (int j = 0; j < 4; ++j) {
      int qabs = qrow_w + g4 * 4 + j;
      Ctx[(size_t)qabs * DIM + h * HD + db * 16 + l16] = (bf16)(oacc[db][j] / l_r[j]);
    }
}

extern "C" void kernel_launch(void* const* d_in, const int* in_sizes, int n_in,
                              void* d_out, int out_size, void* d_ws, size_t ws_size,
                              hipStream_t stream) {
  const float* query = (const float*)d_in[0];
  const float* key   = (const float*)d_in[1];
  const float* value = (const float*)d_in[2];
  const int*   amask = (const int*)d_in[3];
  const float* Wq = (const float*)d_in[4];
  const float* bq = (const float*)d_in[5];
  const float* Wk = (const float*)d_in[6];
  const float* bk = (const float*)d_in[7];
  const float* Wv = (const float*)d_in[8];
  const float* bv = (const float*)d_in[9];
  const float* Wo = (const float*)d_in[10];
  const float* bo = (const float*)d_in[11];
  const float* ln_g = (const float*)d_in[12];
  const float* ln_b = (const float*)d_in[13];

  char* ws = (char*)d_ws;
  bf16* qln = (bf16*)ws;      ws += (size_t)NB * QLEN * DIM * 2;
  bf16* Qp  = (bf16*)ws;      ws += (size_t)NB * QLEN * DIM * 2;
  bf16* Kp  = (bf16*)ws;      ws += (size_t)NB * KVL * DIM * 2;
  bf16* Vp  = (bf16*)ws;      ws += (size_t)NB * KVL * DIM * 2;
  bf16* Ctx = (bf16*)ws;      ws += (size_t)NB * QLEN * DIM * 2;
  unsigned* mbits = (unsigned*)ws;

  ln_q<<<NB * QLEN / 4, 256, 0, stream>>>(query, ln_g, ln_b, qln);
  pack_mask<<<1024, 256, 0, stream>>>(amask, mbits);

  gemm_bt<true,  true><<<(NB * QLEN / 128) * (DIM / 64), 256, 0, stream>>>(qln,   Wq, bq, Qp);
  gemm_bt<false, true><<<(NB * KVL  / 128) * (DIM / 64), 256, 0, stream>>>(key,   Wk, bk, Kp);
  gemm_bt<false, true><<<(NB * KVL  / 128) * (DIM / 64), 256, 0, stream>>>(value, Wv, bv, Vp);

  attn<<<dim3(NH, QLEN / 64, NB), 256, 0, stream>>>(Qp, Kp, Vp, mbits, Ctx);

  gemm_bt<true, false><<<(NB * QLEN / 128) * (DIM / 64), 256, 0, stream>>>(Ctx, Wo, bo, (float*)d_out);
}

// Round 4
// 569.109 us; speedup vs baseline: 1.1945x; 1.1945x over previous
//
#include <hip/hip_runtime.h>
#include <hip/hip_bf16.h>

typedef __bf16 bf16;
typedef bf16 bf16x8 __attribute__((ext_vector_type(8)));
typedef bf16 bf16x4 __attribute__((ext_vector_type(4)));
typedef float f32x4 __attribute__((ext_vector_type(4)));

#define NB 8
#define QLEN 512
#define KVL 4096
#define DIM 768
#define NH 12
#define HD 64

// ---------------- LayerNorm(query) -> bf16 ----------------
__global__ __launch_bounds__(256) void ln_q(const float* __restrict__ x,
    const float* __restrict__ g, const float* __restrict__ beta,
    bf16* __restrict__ out)
{
  int row  = blockIdx.x * 4 + (threadIdx.x >> 6);
  int lane = threadIdx.x & 63;
  const float* rp = x + (size_t)row * DIM;
  f32x4 v[3];
  float s = 0.f, s2 = 0.f;
#pragma unroll
  for (int i = 0; i < 3; ++i) {
    v[i] = *reinterpret_cast<const f32x4*>(rp + (i * 64 + lane) * 4);
#pragma unroll
    for (int j = 0; j < 4; ++j) { s += v[i][j]; s2 += v[i][j] * v[i][j]; }
  }
#pragma unroll
  for (int o = 1; o < 64; o <<= 1) { s += __shfl_xor(s, o); s2 += __shfl_xor(s2, o); }
  float mean = s * (1.f / 768.f);
  float var  = s2 * (1.f / 768.f) - mean * mean;
  float rstd = rsqrtf(var + 1e-5f);
#pragma unroll
  for (int i = 0; i < 3; ++i) {
    int c = (i * 64 + lane) * 4;
    f32x4 gg = *reinterpret_cast<const f32x4*>(g + c);
    f32x4 bb = *reinterpret_cast<const f32x4*>(beta + c);
    bf16x4 o4;
#pragma unroll
    for (int j = 0; j < 4; ++j) o4[j] = (bf16)((v[i][j] - mean) * rstd * gg[j] + bb[j]);
    *reinterpret_cast<bf16x4*>(out + (size_t)row * DIM + c) = o4;
  }
}

// ---------------- mask int32 -> bitmask (bit=1 means masked out) ----------------
__global__ __launch_bounds__(256) void pack_mask(const int* __restrict__ m,
                                                 unsigned* __restrict__ bits)
{
  const int total = NB * QLEN * KVL;
  int stride = gridDim.x * blockDim.x;
  for (int i = blockIdx.x * blockDim.x + threadIdx.x; i < total; i += stride) {
    unsigned long long bal = __ballot(m[i] == 1);
    int lane = threadIdx.x & 63;
    if ((lane & 31) == 0)
      bits[i >> 5] = (unsigned)(bal >> (lane & 32));
  }
}

// ---------------- GEMM: Out[M,768] = A[M,768] @ W[768,768]^T + bias ----------------
// tile 128x128, BK=64, 256 threads = 4 waves (2x2), each wave 64x64 via 4x4 frags
// of mfma_f32_16x16x32_bf16. XCD-grouped block swizzle.
template<bool A_IS_BF16, bool OUT_BF16>
__global__ __launch_bounds__(256) void gemm128(const void* __restrict__ Aptr,
    const float* __restrict__ W, const float* __restrict__ bias,
    void* __restrict__ Out)
{
  const int K = 768, N = 768;
  __shared__ __align__(16) bf16 a_s[128][72];
  __shared__ __align__(16) bf16 b_s[128][72];
  int raw = blockIdx.x;
  int nt = (raw >> 3) % 6;
  int mt = ((raw >> 3) / 6) * 8 + (raw & 7);
  int m0 = mt * 128, n0 = nt * 128;
  int tid = threadIdx.x;
  int lane = tid & 63, wid = tid >> 6;
  int l16 = lane & 15, g4 = lane >> 4;
  int wm = wid >> 1, wn = wid & 1;
  f32x4 acc[4][4] = {};

  for (int k0 = 0; k0 < K; k0 += 64) {
#pragma unroll
    for (int i = 0; i < 4; ++i) {
      int oct = tid + i * 256;
      int row = oct >> 3, col = (oct & 7) * 8;
      bf16x8 av;
      if constexpr (A_IS_BF16) {
        av = *reinterpret_cast<const bf16x8*>((const bf16*)Aptr + (size_t)(m0 + row) * K + k0 + col);
      } else {
        const float* ap = (const float*)Aptr + (size_t)(m0 + row) * K + k0 + col;
        f32x4 f0 = *reinterpret_cast<const f32x4*>(ap);
        f32x4 f1 = *reinterpret_cast<const f32x4*>(ap + 4);
#pragma unroll
        for (int j = 0; j < 4; ++j) { av[j] = (bf16)f0[j]; av[4 + j] = (bf16)f1[j]; }
      }
      *reinterpret_cast<bf16x8*>(&a_s[row][col]) = av;

      const float* wp = W + (size_t)(n0 + row) * K + k0 + col;
      f32x4 f0 = *reinterpret_cast<const f32x4*>(wp);
      f32x4 f1 = *reinterpret_cast<const f32x4*>(wp + 4);
      bf16x8 bv;
#pragma unroll
      for (int j = 0; j < 4; ++j) { bv[j] = (bf16)f0[j]; bv[4 + j] = (bf16)f1[j]; }
      *reinterpret_cast<bf16x8*>(&b_s[row][col]) = bv;
    }
    __syncthreads();
#pragma unroll
    for (int kk = 0; kk < 2; ++kk) {
      bf16x8 af[4], bfv[4];
#pragma unroll
      for (int mi = 0; mi < 4; ++mi)
        af[mi] = *reinterpret_cast<const bf16x8*>(&a_s[wm * 64 + mi * 16 + l16][kk * 32 + g4 * 8]);
#pragma unroll
      for (int ni = 0; ni < 4; ++ni)
        bfv[ni] = *reinterpret_cast<const bf16x8*>(&b_s[wn * 64 + ni * 16 + l16][kk * 32 + g4 * 8]);
#pragma unroll
      for (int mi = 0; mi < 4; ++mi)
#pragma unroll
        for (int ni = 0; ni < 4; ++ni)
          acc[mi][ni] = __builtin_amdgcn_mfma_f32_16x16x32_bf16(af[mi], bfv[ni], acc[mi][ni], 0, 0, 0);
    }
    __syncthreads();
  }
#pragma unroll
  for (int mi = 0; mi < 4; ++mi)
#pragma unroll
    for (int ni = 0; ni < 4; ++ni) {
      int col = n0 + wn * 64 + ni * 16 + l16;
      float bv = bias[col];
#pragma unroll
      for (int j = 0; j < 4; ++j) {
        int row = m0 + wm * 64 + mi * 16 + g4 * 4 + j;
        float v = acc[mi][ni][j] + bv;
        if constexpr (OUT_BF16) ((bf16*)Out)[(size_t)row * N + col] = (bf16)v;
        else                    ((float*)Out)[(size_t)row * N + col] = v;
      }
    }
}

// ---------------- fused masked flash attention (round-1 VERIFIED version) ----------------
// grid (h=12, qtile=8, b=8), 256 threads = 4 waves, each wave owns 16 q rows.
// KV tiles of 32; K staged row-major in LDS, V staged transposed.
__global__ __launch_bounds__(256) void attn(const bf16* __restrict__ Qp,
    const bf16* __restrict__ Kp, const bf16* __restrict__ Vp,
    const unsigned* __restrict__ mbits, bf16* __restrict__ Ctx)
{
  int h = blockIdx.x, qt = blockIdx.y, b = blockIdx.z;
  int tid = threadIdx.x, lane = tid & 63, wid = tid >> 6;
  int g4 = lane >> 4, l16 = lane & 15;
  __shared__ __align__(16) bf16 k_s[32][72];
  __shared__ __align__(16) bf16 v_s[64][40];
  __shared__ __align__(16) bf16 p_s[4][16][40];

  int qrow_w = b * QLEN + qt * 64 + wid * 16;  // wave's first q row (absolute)

  bf16x8 qf[2];
#pragma unroll
  for (int kk = 0; kk < 2; ++kk)
    qf[kk] = *reinterpret_cast<const bf16x8*>(Qp + (size_t)(qrow_w + l16) * DIM + h * HD + kk * 32 + g4 * 8);

  f32x4 oacc[4] = {};
  float m_r[4], l_r[4];
#pragma unroll
  for (int j = 0; j < 4; ++j) { m_r[j] = -1e30f; l_r[j] = 0.f; }

  const bf16* Kb = Kp + (size_t)b * KVL * DIM + h * HD;
  const bf16* Vb = Vp + (size_t)b * KVL * DIM + h * HD;

  for (int kv0 = 0; kv0 < KVL; kv0 += 32) {
    // stage K tile 32x64
    {
      int row = tid >> 3, col = (tid & 7) * 8;
      *reinterpret_cast<bf16x8*>(&k_s[row][col]) =
          *reinterpret_cast<const bf16x8*>(Kb + (size_t)(kv0 + row) * DIM + col);
    }
    // stage V tile transposed: v_s[d][kv]
    {
      int kv = tid & 31, d0 = (tid >> 5) * 8;
      bf16x8 v = *reinterpret_cast<const bf16x8*>(Vb + (size_t)(kv0 + kv) * DIM + d0);
#pragma unroll
      for (int j = 0; j < 8; ++j) v_s[d0 + j][kv] = v[j];
    }
    __syncthreads();

    // S = Q K^T  (two 16-col blocks)
    f32x4 sacc[2] = {};
#pragma unroll
    for (int nb = 0; nb < 2; ++nb)
#pragma unroll
      for (int kk = 0; kk < 2; ++kk) {
        bf16x8 kf = *reinterpret_cast<const bf16x8*>(&k_s[nb * 16 + l16][kk * 32 + g4 * 8]);
        sacc[nb] = __builtin_amdgcn_mfma_f32_16x16x32_bf16(qf[kk], kf, sacc[nb], 0, 0, 0);
      }

    // mask + online softmax (rows j, 16-lane-group reduce over kv)
    float p[2][4], corr[4];
#pragma unroll
    for (int j = 0; j < 4; ++j) {
      int qabs = qrow_w + g4 * 4 + j;
      unsigned w = mbits[(size_t)qabs * (KVL / 32) + (kv0 >> 5)];
      float s0 = ((w >> l16) & 1u) ? -1e30f : sacc[0][j] * 0.125f;
      float s1 = ((w >> (16 + l16)) & 1u) ? -1e30f : sacc[1][j] * 0.125f;
      float tm = fmaxf(s0, s1);
#pragma unroll
      for (int o = 1; o < 16; o <<= 1) tm = fmaxf(tm, __shfl_xor(tm, o));
      float mnew = fmaxf(m_r[j], tm);
      corr[j] = __expf(m_r[j] - mnew);
      m_r[j] = mnew;
      float p0 = __expf(s0 - mnew);
      float p1 = __expf(s1 - mnew);
      p[0][j] = p0; p[1][j] = p1;
      float ts = p0 + p1;
#pragma unroll
      for (int o = 1; o < 16; o <<= 1) ts += __shfl_xor(ts, o);
      l_r[j] = l_r[j] * corr[j] + ts;
    }

    // P -> per-wave LDS (C-frag layout -> A-frag layout)
#pragma unroll
    for (int nb = 0; nb < 2; ++nb)
#pragma unroll
      for (int j = 0; j < 4; ++j)
        p_s[wid][g4 * 4 + j][nb * 16 + l16] = (bf16)p[nb][j];

    // rescale O accumulators
#pragma unroll
    for (int db = 0; db < 4; ++db)
#pragma unroll
      for (int j = 0; j < 4; ++j) oacc[db][j] *= corr[j];

    // O += P V
    bf16x8 pf = *reinterpret_cast<const bf16x8*>(&p_s[wid][l16][g4 * 8]);
#pragma unroll
    for (int db = 0; db < 4; ++db) {
      bf16x8 vf = *reinterpret_cast<const bf16x8*>(&v_s[db * 16 + l16][g4 * 8]);
      oacc[db] = __builtin_amdgcn_mfma_f32_16x16x32_bf16(pf, vf, oacc[db], 0, 0, 0);
    }
    __syncthreads();
  }

  // epilogue: Ctx[q][h*64 + d] = O / l
#pragma unroll
  for (int db = 0; db < 4; ++db)
#pragma unroll
    for (int j = 0; j < 4; ++j) {
      int qabs = qrow_w + g4 * 4 + j;
      Ctx[(size_t)qabs * DIM + h * HD + db * 16 + l16] = (bf16)(oacc[db][j] / l_r[j]);
    }
}

extern "C" void kernel_launch(void* const* d_in, const int* in_sizes, int n_in,
                              void* d_out, int out_size, void* d_ws, size_t ws_size,
                              hipStream_t stream) {
  const float* query = (const float*)d_in[0];
  const float* key   = (const float*)d_in[1];
  const float* value = (const float*)d_in[2];
  const int*   amask = (const int*)d_in[3];
  const float* Wq = (const float*)d_in[4];
  const float* bq = (const float*)d_in[5];
  const float* Wk = (const float*)d_in[6];
  const float* bk = (const float*)d_in[7];
  const float* Wv = (const float*)d_in[8];
  const float* bv = (const float*)d_in[9];
  const float* Wo = (const float*)d_in[10];
  const float* bo = (const float*)d_in[11];
  const float* ln_g = (const float*)d_in[12];
  const float* ln_b = (const float*)d_in[13];

  char* ws = (char*)d_ws;
  bf16* qln = (bf16*)ws;      ws += (size_t)NB * QLEN * DIM * 2;
  bf16* Qp  = (bf16*)ws;      ws += (size_t)NB * QLEN * DIM * 2;
  bf16* Kp  = (bf16*)ws;      ws += (size_t)NB * KVL * DIM * 2;
  bf16* Vp  = (bf16*)ws;      ws += (size_t)NB * KVL * DIM * 2;
  bf16* Ctx = (bf16*)ws;      ws += (size_t)NB * QLEN * DIM * 2;
  unsigned* mbits = (unsigned*)ws;

  ln_q<<<NB * QLEN / 4, 256, 0, stream>>>(query, ln_g, ln_b, qln);
  pack_mask<<<1024, 256, 0, stream>>>(amask, mbits);

  gemm128<true,  true><<<(NB * QLEN / 128) * 6, 256, 0, stream>>>(qln,   Wq, bq, Qp);
  gemm128<false, true><<<(NB * KVL  / 128) * 6, 256, 0, stream>>>(key,   Wk, bk, Kp);
  gemm128<false, true><<<(NB * KVL  / 128) * 6, 256, 0, stream>>>(value, Wv, bv, Vp);

  attn<<<dim3(NH, QLEN / 64, NB), 256, 0, stream>>>(Qp, Kp, Vp, mbits, Ctx);

  gemm128<true, false><<<(NB * QLEN / 128) * 6, 256, 0, stream>>>(Ctx, Wo, bo, (float*)d_out);
}

// Round 5
// 525.980 us; speedup vs baseline: 1.2925x; 1.0820x over previous
//
#include <hip/hip_runtime.h>
#include <hip/hip_bf16.h>

typedef __bf16 bf16;
typedef bf16 bf16x8 __attribute__((ext_vector_type(8)));
typedef bf16 bf16x4 __attribute__((ext_vector_type(4)));
typedef float f32x4 __attribute__((ext_vector_type(4)));

#define NB 8
#define QLEN 512
#define KVL 4096
#define DIM 768
#define NH 12
#define HD 64

// ---------------- LayerNorm(query) -> bf16 ----------------
__global__ __launch_bounds__(256) void ln_q(const float* __restrict__ x,
    const float* __restrict__ g, const float* __restrict__ beta,
    bf16* __restrict__ out)
{
  int row  = blockIdx.x * 4 + (threadIdx.x >> 6);
  int lane = threadIdx.x & 63;
  const float* rp = x + (size_t)row * DIM;
  f32x4 v[3];
  float s = 0.f, s2 = 0.f;
#pragma unroll
  for (int i = 0; i < 3; ++i) {
    v[i] = *reinterpret_cast<const f32x4*>(rp + (i * 64 + lane) * 4);
#pragma unroll
    for (int j = 0; j < 4; ++j) { s += v[i][j]; s2 += v[i][j] * v[i][j]; }
  }
#pragma unroll
  for (int o = 1; o < 64; o <<= 1) { s += __shfl_xor(s, o); s2 += __shfl_xor(s2, o); }
  float mean = s * (1.f / 768.f);
  float var  = s2 * (1.f / 768.f) - mean * mean;
  float rstd = rsqrtf(var + 1e-5f);
#pragma unroll
  for (int i = 0; i < 3; ++i) {
    int c = (i * 64 + lane) * 4;
    f32x4 gg = *reinterpret_cast<const f32x4*>(g + c);
    f32x4 bb = *reinterpret_cast<const f32x4*>(beta + c);
    bf16x4 o4;
#pragma unroll
    for (int j = 0; j < 4; ++j) o4[j] = (bf16)((v[i][j] - mean) * rstd * gg[j] + bb[j]);
    *reinterpret_cast<bf16x4*>(out + (size_t)row * DIM + c) = o4;
  }
}

// ---------------- mask int32 -> bitmask (bit=1 means masked out) ----------------
__global__ __launch_bounds__(256) void pack_mask(const int* __restrict__ m,
                                                 unsigned* __restrict__ bits)
{
  const int total = NB * QLEN * KVL;
  int stride = gridDim.x * blockDim.x;
  for (int i = blockIdx.x * blockDim.x + threadIdx.x; i < total; i += stride) {
    unsigned long long bal = __ballot(m[i] == 1);
    int lane = threadIdx.x & 63;
    if ((lane & 31) == 0)
      bits[i >> 5] = (unsigned)(bal >> (lane & 32));
  }
}

// ---------------- GEMM: Out[M,768] = A[M,768] @ W[768,768]^T + bias ----------------
// (hardware-verified in round 4)
template<bool A_IS_BF16, bool OUT_BF16>
__global__ __launch_bounds__(256) void gemm128(const void* __restrict__ Aptr,
    const float* __restrict__ W, const float* __restrict__ bias,
    void* __restrict__ Out)
{
  const int K = 768, N = 768;
  __shared__ __align__(16) bf16 a_s[128][72];
  __shared__ __align__(16) bf16 b_s[128][72];
  int raw = blockIdx.x;
  int nt = (raw >> 3) % 6;
  int mt = ((raw >> 3) / 6) * 8 + (raw & 7);
  int m0 = mt * 128, n0 = nt * 128;
  int tid = threadIdx.x;
  int lane = tid & 63, wid = tid >> 6;
  int l16 = lane & 15, g4 = lane >> 4;
  int wm = wid >> 1, wn = wid & 1;
  f32x4 acc[4][4] = {};

  for (int k0 = 0; k0 < K; k0 += 64) {
#pragma unroll
    for (int i = 0; i < 4; ++i) {
      int oct = tid + i * 256;
      int row = oct >> 3, col = (oct & 7) * 8;
      bf16x8 av;
      if constexpr (A_IS_BF16) {
        av = *reinterpret_cast<const bf16x8*>((const bf16*)Aptr + (size_t)(m0 + row) * K + k0 + col);
      } else {
        const float* ap = (const float*)Aptr + (size_t)(m0 + row) * K + k0 + col;
        f32x4 f0 = *reinterpret_cast<const f32x4*>(ap);
        f32x4 f1 = *reinterpret_cast<const f32x4*>(ap + 4);
#pragma unroll
        for (int j = 0; j < 4; ++j) { av[j] = (bf16)f0[j]; av[4 + j] = (bf16)f1[j]; }
      }
      *reinterpret_cast<bf16x8*>(&a_s[row][col]) = av;

      const float* wp = W + (size_t)(n0 + row) * K + k0 + col;
      f32x4 f0 = *reinterpret_cast<const f32x4*>(wp);
      f32x4 f1 = *reinterpret_cast<const f32x4*>(wp + 4);
      bf16x8 bv;
#pragma unroll
      for (int j = 0; j < 4; ++j) { bv[j] = (bf16)f0[j]; bv[4 + j] = (bf16)f1[j]; }
      *reinterpret_cast<bf16x8*>(&b_s[row][col]) = bv;
    }
    __syncthreads();
#pragma unroll
    for (int kk = 0; kk < 2; ++kk) {
      bf16x8 af[4], bfv[4];
#pragma unroll
      for (int mi = 0; mi < 4; ++mi)
        af[mi] = *reinterpret_cast<const bf16x8*>(&a_s[wm * 64 + mi * 16 + l16][kk * 32 + g4 * 8]);
#pragma unroll
      for (int ni = 0; ni < 4; ++ni)
        bfv[ni] = *reinterpret_cast<const bf16x8*>(&b_s[wn * 64 + ni * 16 + l16][kk * 32 + g4 * 8]);
#pragma unroll
      for (int mi = 0; mi < 4; ++mi)
#pragma unroll
        for (int ni = 0; ni < 4; ++ni)
          acc[mi][ni] = __builtin_amdgcn_mfma_f32_16x16x32_bf16(af[mi], bfv[ni], acc[mi][ni], 0, 0, 0);
    }
    __syncthreads();
  }
#pragma unroll
  for (int mi = 0; mi < 4; ++mi)
#pragma unroll
    for (int ni = 0; ni < 4; ++ni) {
      int col = n0 + wn * 64 + ni * 16 + l16;
      float bv = bias[col];
#pragma unroll
      for (int j = 0; j < 4; ++j) {
        int row = m0 + wm * 64 + mi * 16 + g4 * 4 + j;
        float v = acc[mi][ni][j] + bv;
        if constexpr (OUT_BF16) ((bf16*)Out)[(size_t)row * N + col] = (bf16)v;
        else                    ((float*)Out)[(size_t)row * N + col] = v;
      }
    }
}

// ---------------- fused masked flash attention v3: swapped-operand 16x16 ----------------
// Same staging/LDS/loads as the round-1 verified kernel. S^T = mfma(kf, qf):
// C col = l16 = q, C row = g4*4+r = kv_local -> per-lane softmax over own q-row
// (8 kv in regs, + shfl_xor(16) + shfl_xor(32) for the cross-group reduce).
// PV: O^T = mfma(vf, pf): O col = l16 = q keeps stats lane-scalar.
// P redistribution to PV B-frag: 2-stage butterfly (xor16 assemble, xor32 route).
__global__ __launch_bounds__(256) void attn(const bf16* __restrict__ Qp,
    const bf16* __restrict__ Kp, const bf16* __restrict__ Vp,
    const unsigned* __restrict__ mbits, bf16* __restrict__ Ctx)
{
  int h = blockIdx.x, qt = blockIdx.y, b = blockIdx.z;
  int tid = threadIdx.x, lane = tid & 63, wid = tid >> 6;
  int g4 = lane >> 4, l16 = lane & 15;
  __shared__ __align__(16) bf16 k_s[32][72];
  __shared__ __align__(16) bf16 v_s[64][40];
  __shared__ __align__(16) bf16 o_s[4][16][72];

  int qrow_w = b * QLEN + qt * 64 + wid * 16;  // wave's first q row (absolute)
  int q = qrow_w + l16;                        // this lane's q row

  // Q fragment, pre-scaled by 1/8 (exact in bf16: exponent shift)
  bf16x8 qf[2];
#pragma unroll
  for (int kk = 0; kk < 2; ++kk) {
    bf16x8 t = *reinterpret_cast<const bf16x8*>(Qp + (size_t)q * DIM + h * HD + kk * 32 + g4 * 8);
#pragma unroll
    for (int j = 0; j < 8; ++j) qf[kk][j] = (bf16)((float)t[j] * 0.125f);
  }

  const bf16* Kb = Kp + (size_t)b * KVL * DIM + h * HD;
  const bf16* Vb = Vp + (size_t)b * KVL * DIM + h * HD;
  const unsigned* mrow = mbits + (size_t)q * (KVL / 32);

  f32x4 oacc[4] = {};                          // O^T[d = db*16+g4*4+r][q = l16]
  float m_r = -1e30f, l_r = 0.f;

  bool odd = (g4 & 1) != 0;
  bool hiS = (g4 >> 1) != 0;
  bool keep = (g4 == 0) || (g4 == 3);

  for (int kv0 = 0; kv0 < KVL; kv0 += 32) {
    // stage K tile 32x64 (one b128 store per thread)
    {
      int row = tid >> 3, col = (tid & 7) * 8;
      *reinterpret_cast<bf16x8*>(&k_s[row][col]) =
          *reinterpret_cast<const bf16x8*>(Kb + (size_t)(kv0 + row) * DIM + col);
    }
    // stage V tile transposed: v_s[d][kv]
    {
      int kv = tid & 31, d0 = (tid >> 5) * 8;
      bf16x8 v = *reinterpret_cast<const bf16x8*>(Vb + (size_t)(kv0 + kv) * DIM + d0);
#pragma unroll
      for (int j = 0; j < 8; ++j) v_s[d0 + j][kv] = v[j];
    }
    __syncthreads();

    // ---- S^T = K . Q : sacc[nb] rows = kv_local nb*16 + g4*4 + r, col = q ----
    f32x4 sacc[2] = {};
#pragma unroll
    for (int nb = 0; nb < 2; ++nb)
#pragma unroll
      for (int kk = 0; kk < 2; ++kk) {
        bf16x8 kf = *reinterpret_cast<const bf16x8*>(&k_s[nb * 16 + l16][kk * 32 + g4 * 8]);
        sacc[nb] = __builtin_amdgcn_mfma_f32_16x16x32_bf16(kf, qf[kk], sacc[nb], 0, 0, 0);
      }

    // ---- mask (per-lane word for this q row) ----
    unsigned w = mrow[kv0 >> 5];
    float sv[8];   // sv[nb*4+r]: kv = nb*16 + g4*4 + r
#pragma unroll
    for (int nb = 0; nb < 2; ++nb)
#pragma unroll
      for (int r = 0; r < 4; ++r) {
        int bit = nb * 16 + g4 * 4 + r;
        sv[nb * 4 + r] = ((w >> bit) & 1u) ? -1e30f : sacc[nb][r];
      }

    // ---- tile max: in-reg tree + 2 shfl ----
    float tm = fmaxf(fmaxf(fmaxf(sv[0], sv[1]), fmaxf(sv[2], sv[3])),
                     fmaxf(fmaxf(sv[4], sv[5]), fmaxf(sv[6], sv[7])));
    tm = fmaxf(tm, __shfl_xor(tm, 16));
    tm = fmaxf(tm, __shfl_xor(tm, 32));

    // ---- online update (T13: skip rescale when no row's max grew) ----
    if (!__all(tm <= m_r)) {
      float mnew = fmaxf(m_r, tm);
      float corr = __expf(m_r - mnew);
      m_r = mnew;
      l_r *= corr;
#pragma unroll
      for (int db = 0; db < 4; ++db)
#pragma unroll
        for (int r = 0; r < 4; ++r) oacc[db][r] *= corr;
    }
    float p[8];
#pragma unroll
    for (int i = 0; i < 8; ++i) p[i] = __expf(sv[i] - m_r);
    float ts = ((p[0] + p[1]) + (p[2] + p[3])) + ((p[4] + p[5]) + (p[6] + p[7]));
    ts += __shfl_xor(ts, 16);
    ts += __shfl_xor(ts, 32);
    l_r += ts;

    // ---- P redistribution: own kv = (r>>2)*16 + g4*4 + (r&3)  ->  pf[j] = P[q][8*g4+j]
    // stage 1 (xor16): full pair exchange; assemble slice octets; stage 2 (xor32): route.
    float q16[8];
#pragma unroll
    for (int r = 0; r < 8; ++r) q16[r] = __shfl_xor(p[r], 16);
    float octA[8], octB[8];
#pragma unroll
    for (int j = 0; j < 4; ++j) {
      float lo_lo = odd ? q16[j]     : p[j];        // group g4&~1, regs j   (slice0)
      float lo_hi = odd ? q16[4 + j] : p[4 + j];    // group g4&~1, regs 4+j (slice1)
      float hi_lo = odd ? p[j]       : q16[j];      // group g4|1,  regs j
      float hi_hi = odd ? p[4 + j]   : q16[4 + j];  // group g4|1,  regs 4+j
      octA[j]     = hiS ? lo_hi : lo_lo;
      octA[4 + j] = hiS ? hi_hi : hi_lo;
      octB[j]     = hiS ? lo_lo : lo_hi;
      octB[4 + j] = hiS ? hi_lo : hi_hi;
    }
    bf16x8 pf;
#pragma unroll
    for (int j = 0; j < 8; ++j) {
      float rv = __shfl_xor(octB[j], 32);
      pf[j] = (bf16)(keep ? octA[j] : rv);
    }

    // ---- O^T += V^T . P : one mfma per 16-d block (K-dim = 32 kv) ----
#pragma unroll
    for (int db = 0; db < 4; ++db) {
      bf16x8 vf = *reinterpret_cast<const bf16x8*>(&v_s[db * 16 + l16][g4 * 8]);
      oacc[db] = __builtin_amdgcn_mfma_f32_16x16x32_bf16(vf, pf, oacc[db], 0, 0, 0);
    }
    __syncthreads();
  }

  // ---- epilogue: transpose via per-wave LDS, coalesced bf16x8 stores ----
  float inv = 1.f / l_r;
#pragma unroll
  for (int db = 0; db < 4; ++db) {
    bf16x4 t;
#pragma unroll
    for (int r = 0; r < 4; ++r) t[r] = (bf16)(oacc[db][r] * inv);
    *reinterpret_cast<bf16x4*>(&o_s[wid][l16][db * 16 + g4 * 4]) = t;
  }
  // wave-internal LDS RAW handled by compiler waitcnt (same-wave, as p_s in round 1)
#pragma unroll
  for (int pass = 0; pass < 2; ++pass) {
    int row = (lane >> 3) + pass * 8;
    int c8 = (lane & 7) * 8;
    bf16x8 v = *reinterpret_cast<const bf16x8*>(&o_s[wid][row][c8]);
    *reinterpret_cast<bf16x8*>(Ctx + (size_t)(qrow_w + row) * DIM + h * HD + c8) = v;
  }
}

extern "C" void kernel_launch(void* const* d_in, const int* in_sizes, int n_in,
                              void* d_out, int out_size, void* d_ws, size_t ws_size,
                              hipStream_t stream) {
  const float* query = (const float*)d_in[0];
  const float* key   = (const float*)d_in[1];
  const float* value = (const float*)d_in[2];
  const int*   amask = (const int*)d_in[3];
  const float* Wq = (const float*)d_in[4];
  const float* bq = (const float*)d_in[5];
  const float* Wk = (const float*)d_in[6];
  const float* bk = (const float*)d_in[7];
  const float* Wv = (const float*)d_in[8];
  const float* bv = (const float*)d_in[9];
  const float* Wo = (const float*)d_in[10];
  const float* bo = (const float*)d_in[11];
  const float* ln_g = (const float*)d_in[12];
  const float* ln_b = (const float*)d_in[13];

  char* ws = (char*)d_ws;
  bf16* qln = (bf16*)ws;      ws += (size_t)NB * QLEN * DIM * 2;
  bf16* Qp  = (bf16*)ws;      ws += (size_t)NB * QLEN * DIM * 2;
  bf16* Kp  = (bf16*)ws;      ws += (size_t)NB * KVL * DIM * 2;
  bf16* Vp  = (bf16*)ws;      ws += (size_t)NB * KVL * DIM * 2;
  bf16* Ctx = (bf16*)ws;      ws += (size_t)NB * QLEN * DIM * 2;
  unsigned* mbits = (unsigned*)ws;

  ln_q<<<NB * QLEN / 4, 256, 0, stream>>>(query, ln_g, ln_b, qln);
  pack_mask<<<1024, 256, 0, stream>>>(amask, mbits);

  gemm128<true,  true><<<(NB * QLEN / 128) * 6, 256, 0, stream>>>(qln,   Wq, bq, Qp);
  gemm128<false, true><<<(NB * KVL  / 128) * 6, 256, 0, stream>>>(key,   Wk, bk, Kp);
  gemm128<false, true><<<(NB * KVL  / 128) * 6, 256, 0, stream>>>(value, Wv, bv, Vp);

  attn<<<dim3(NH, QLEN / 64, NB), 256, 0, stream>>>(Qp, Kp, Vp, mbits, Ctx);

  gemm128<true, false><<<(NB * QLEN / 128) * 6, 256, 0, stream>>>(Ctx, Wo, bo, (float*)d_out);
}

// Round 8
// 481.283 us; speedup vs baseline: 1.4125x; 1.0929x over previous
//
#include <hip/hip_runtime.h>
#include <hip/hip_bf16.h>

typedef __bf16 bf16;
typedef bf16 bf16x8 __attribute__((ext_vector_type(8)));
typedef bf16 bf16x4 __attribute__((ext_vector_type(4)));
typedef float f32x4 __attribute__((ext_vector_type(4)));

#define NB 8
#define QLEN 512
#define KVL 4096
#define DIM 768
#define NH 12
#define HD 64

// ---------------- LayerNorm(query) -> bf16 ----------------
__global__ __launch_bounds__(256) void ln_q(const float* __restrict__ x,
    const float* __restrict__ g, const float* __restrict__ beta,
    bf16* __restrict__ out)
{
  int row  = blockIdx.x * 4 + (threadIdx.x >> 6);
  int lane = threadIdx.x & 63;
  const float* rp = x + (size_t)row * DIM;
  f32x4 v[3];
  float s = 0.f, s2 = 0.f;
#pragma unroll
  for (int i = 0; i < 3; ++i) {
    v[i] = *reinterpret_cast<const f32x4*>(rp + (i * 64 + lane) * 4);
#pragma unroll
    for (int j = 0; j < 4; ++j) { s += v[i][j]; s2 += v[i][j] * v[i][j]; }
  }
#pragma unroll
  for (int o = 1; o < 64; o <<= 1) { s += __shfl_xor(s, o); s2 += __shfl_xor(s2, o); }
  float mean = s * (1.f / 768.f);
  float var  = s2 * (1.f / 768.f) - mean * mean;
  float rstd = rsqrtf(var + 1e-5f);
#pragma unroll
  for (int i = 0; i < 3; ++i) {
    int c = (i * 64 + lane) * 4;
    f32x4 gg = *reinterpret_cast<const f32x4*>(g + c);
    f32x4 bb = *reinterpret_cast<const f32x4*>(beta + c);
    bf16x4 o4;
#pragma unroll
    for (int j = 0; j < 4; ++j) o4[j] = (bf16)((v[i][j] - mean) * rstd * gg[j] + bb[j]);
    *reinterpret_cast<bf16x4*>(out + (size_t)row * DIM + c) = o4;
  }
}

// ---------------- mask int32 -> bitmask (bit=1 means masked out) ----------------
__global__ __launch_bounds__(256) void pack_mask(const int* __restrict__ m,
                                                 unsigned* __restrict__ bits)
{
  const int total = NB * QLEN * KVL;
  int stride = gridDim.x * blockDim.x;
  for (int i = blockIdx.x * blockDim.x + threadIdx.x; i < total; i += stride) {
    unsigned long long bal = __ballot(m[i] == 1);
    int lane = threadIdx.x & 63;
    if ((lane & 31) == 0)
      bits[i >> 5] = (unsigned)(bal >> (lane & 32));
  }
}

// ---------------- GEMM: Out[M,768] = A[M,768] @ W[768,768]^T + bias ----------------
// (hardware-verified rounds 4/5: f32 W, convert during staging)
template<bool A_IS_BF16, bool OUT_BF16>
__global__ __launch_bounds__(256) void gemm128(const void* __restrict__ Aptr,
    const float* __restrict__ W, const float* __restrict__ bias,
    void* __restrict__ Out)
{
  const int K = 768, N = 768;
  __shared__ __align__(16) bf16 a_s[128][72];
  __shared__ __align__(16) bf16 b_s[128][72];
  int raw = blockIdx.x;
  int nt = (raw >> 3) % 6;
  int mt = ((raw >> 3) / 6) * 8 + (raw & 7);
  int m0 = mt * 128, n0 = nt * 128;
  int tid = threadIdx.x;
  int lane = tid & 63, wid = tid >> 6;
  int l16 = lane & 15, g4 = lane >> 4;
  int wm = wid >> 1, wn = wid & 1;
  f32x4 acc[4][4] = {};

  for (int k0 = 0; k0 < K; k0 += 64) {
#pragma unroll
    for (int i = 0; i < 4; ++i) {
      int oct = tid + i * 256;
      int row = oct >> 3, col = (oct & 7) * 8;
      bf16x8 av;
      if constexpr (A_IS_BF16) {
        av = *reinterpret_cast<const bf16x8*>((const bf16*)Aptr + (size_t)(m0 + row) * K + k0 + col);
      } else {
        const float* ap = (const float*)Aptr + (size_t)(m0 + row) * K + k0 + col;
        f32x4 f0 = *reinterpret_cast<const f32x4*>(ap);
        f32x4 f1 = *reinterpret_cast<const f32x4*>(ap + 4);
#pragma unroll
        for (int j = 0; j < 4; ++j) { av[j] = (bf16)f0[j]; av[4 + j] = (bf16)f1[j]; }
      }
      *reinterpret_cast<bf16x8*>(&a_s[row][col]) = av;

      const float* wp = W + (size_t)(n0 + row) * K + k0 + col;
      f32x4 f0 = *reinterpret_cast<const f32x4*>(wp);
      f32x4 f1 = *reinterpret_cast<const f32x4*>(wp + 4);
      bf16x8 bv;
#pragma unroll
      for (int j = 0; j < 4; ++j) { bv[j] = (bf16)f0[j]; bv[4 + j] = (bf16)f1[j]; }
      *reinterpret_cast<bf16x8*>(&b_s[row][col]) = bv;
    }
    __syncthreads();
#pragma unroll
    for (int kk = 0; kk < 2; ++kk) {
      bf16x8 af[4], bfv[4];
#pragma unroll
      for (int mi = 0; mi < 4; ++mi)
        af[mi] = *reinterpret_cast<const bf16x8*>(&a_s[wm * 64 + mi * 16 + l16][kk * 32 + g4 * 8]);
#pragma unroll
      for (int ni = 0; ni < 4; ++ni)
        bfv[ni] = *reinterpret_cast<const bf16x8*>(&b_s[wn * 64 + ni * 16 + l16][kk * 32 + g4 * 8]);
#pragma unroll
      for (int mi = 0; mi < 4; ++mi)
#pragma unroll
        for (int ni = 0; ni < 4; ++ni)
          acc[mi][ni] = __builtin_amdgcn_mfma_f32_16x16x32_bf16(af[mi], bfv[ni], acc[mi][ni], 0, 0, 0);
    }
    __syncthreads();
  }
#pragma unroll
  for (int mi = 0; mi < 4; ++mi)
#pragma unroll
    for (int ni = 0; ni < 4; ++ni) {
      int col = n0 + wn * 64 + ni * 16 + l16;
      float bv = bias[col];
#pragma unroll
      for (int j = 0; j < 4; ++j) {
        int row = m0 + wm * 64 + mi * 16 + g4 * 4 + j;
        float v = acc[mi][ni][j] + bv;
        if constexpr (OUT_BF16) ((bf16*)Out)[(size_t)row * N + col] = (bf16)v;
        else                    ((float*)Out)[(size_t)row * N + col] = v;
      }
    }
}

// ---------------- fused masked flash attention v5: KVBLK=64, single-buffer ----------------
// BISECT: v3's verified staging patterns (b128 K rows, scalar V transpose) and
// verified 2-barrier schedule, with ONLY the 64-kv-per-tile math added
// (2 mask words, 16-wide softmax tree, v3 butterfly per 32-kv half, 2 PV mfmas).
__global__ __launch_bounds__(256) void attn(const bf16* __restrict__ Qp,
    const bf16* __restrict__ Kp, const bf16* __restrict__ Vp,
    const unsigned* __restrict__ mbits, bf16* __restrict__ Ctx)
{
  int h = blockIdx.x, qt = blockIdx.y, b = blockIdx.z;
  int tid = threadIdx.x, lane = tid & 63, wid = tid >> 6;
  int g4 = lane >> 4, l16 = lane & 15;
  __shared__ __align__(16) bf16 k_s[64][72];
  __shared__ __align__(16) bf16 v_s[64][72];
  __shared__ __align__(16) bf16 o_s[4][16][72];

  int qrow_w = b * QLEN + qt * 64 + wid * 16;
  int q = qrow_w + l16;                            // this lane's q row

  bf16x8 qf[2];                                    // pre-scaled by 1/8
#pragma unroll
  for (int kk = 0; kk < 2; ++kk) {
    bf16x8 t = *reinterpret_cast<const bf16x8*>(Qp + (size_t)q * DIM + h * HD + kk * 32 + g4 * 8);
#pragma unroll
    for (int j = 0; j < 8; ++j) qf[kk][j] = (bf16)((float)t[j] * 0.125f);
  }

  const bf16* Kb = Kp + (size_t)b * KVL * DIM + h * HD;
  const bf16* Vb = Vp + (size_t)b * KVL * DIM + h * HD;
  const unsigned* mrow = mbits + (size_t)q * (KVL / 32);

  f32x4 oacc[4] = {};                              // O^T[d=db*16+g4*4+r][q=l16]
  float m_r = -1e30f, l_r = 0.f;

  bool odd = (g4 & 1) != 0;
  bool hiS = (g4 >> 1) != 0;
  bool keep = (g4 == 0) || (g4 == 3);

  for (int kv0 = 0; kv0 < KVL; kv0 += 64) {
    // stage K tile 64x64: verified b128 row store, twice
    {
      int row = tid >> 3, col = (tid & 7) * 8;
      *reinterpret_cast<bf16x8*>(&k_s[row][col]) =
          *reinterpret_cast<const bf16x8*>(Kb + (size_t)(kv0 + row) * DIM + col);
      *reinterpret_cast<bf16x8*>(&k_s[row + 32][col]) =
          *reinterpret_cast<const bf16x8*>(Kb + (size_t)(kv0 + row + 32) * DIM + col);
    }
    // stage V tile transposed v_s[d][kv]: verified scalar transpose, twice
    {
      int kv = tid & 31, d0 = (tid >> 5) * 8;
      bf16x8 va = *reinterpret_cast<const bf16x8*>(Vb + (size_t)(kv0 + kv) * DIM + d0);
      bf16x8 vb2 = *reinterpret_cast<const bf16x8*>(Vb + (size_t)(kv0 + kv + 32) * DIM + d0);
#pragma unroll
      for (int j = 0; j < 8; ++j) {
        v_s[d0 + j][kv] = va[j];
        v_s[d0 + j][kv + 32] = vb2[j];
      }
    }
    __syncthreads();

    // ---- S^T = K . Q : 4 kv16-blocks x 2 k-steps ----
    f32x4 sacc[4] = {};
#pragma unroll
    for (int nb = 0; nb < 4; ++nb)
#pragma unroll
      for (int kk = 0; kk < 2; ++kk) {
        bf16x8 kf = *reinterpret_cast<const bf16x8*>(&k_s[nb * 16 + l16][kk * 32 + g4 * 8]);
        sacc[nb] = __builtin_amdgcn_mfma_f32_16x16x32_bf16(kf, qf[kk], sacc[nb], 0, 0, 0);
      }

    // ---- mask: kv = nb*16 + g4*4 + r ----
    unsigned w0 = mrow[kv0 >> 5];
    unsigned w1 = mrow[(kv0 >> 5) + 1];
    float sv[16];
#pragma unroll
    for (int nb = 0; nb < 4; ++nb) {
      unsigned w = (nb < 2) ? w0 : w1;
#pragma unroll
      for (int r = 0; r < 4; ++r) {
        int bit = (nb & 1) * 16 + g4 * 4 + r;
        sv[nb * 4 + r] = ((w >> bit) & 1u) ? -1e30f : sacc[nb][r];
      }
    }

    // ---- tile max: in-reg tree + 2 shfl ----
    float mx[8];
#pragma unroll
    for (int i = 0; i < 8; ++i) mx[i] = fmaxf(sv[i], sv[i + 8]);
#pragma unroll
    for (int i = 0; i < 4; ++i) mx[i] = fmaxf(mx[i], mx[i + 4]);
    float tm = fmaxf(fmaxf(mx[0], mx[1]), fmaxf(mx[2], mx[3]));
    tm = fmaxf(tm, __shfl_xor(tm, 16));
    tm = fmaxf(tm, __shfl_xor(tm, 32));

    if (!__all(tm <= m_r)) {                       // T13 defer-rescale
      float mnew = fmaxf(m_r, tm);
      float corr = __expf(m_r - mnew);
      m_r = mnew;
      l_r *= corr;
#pragma unroll
      for (int db = 0; db < 4; ++db)
#pragma unroll
        for (int r = 0; r < 4; ++r) oacc[db][r] *= corr;
    }
    float p[16];
#pragma unroll
    for (int i = 0; i < 16; ++i) p[i] = __expf(sv[i] - m_r);
    float sm[8];
#pragma unroll
    for (int i = 0; i < 8; ++i) sm[i] = p[i] + p[i + 8];
#pragma unroll
    for (int i = 0; i < 4; ++i) sm[i] += sm[i + 4];
    float ts = (sm[0] + sm[1]) + (sm[2] + sm[3]);
    ts += __shfl_xor(ts, 16);
    ts += __shfl_xor(ts, 32);
    l_r += ts;

    // ---- butterfly on p[0..7] (verbatim round-5 verified code) -> pf0 ----
    bf16x8 pf0, pf1;
    {
      float q16[8];
#pragma unroll
      for (int r = 0; r < 8; ++r) q16[r] = __shfl_xor(p[r], 16);
      float octA[8], octB[8];
#pragma unroll
      for (int j = 0; j < 4; ++j) {
        float lo_lo = odd ? q16[j]     : p[j];
        float lo_hi = odd ? q16[4 + j] : p[4 + j];
        float hi_lo = odd ? p[j]       : q16[j];
        float hi_hi = odd ? p[4 + j]   : q16[4 + j];
        octA[j]     = hiS ? lo_hi : lo_lo;
        octA[4 + j] = hiS ? hi_hi : hi_lo;
        octB[j]     = hiS ? lo_lo : lo_hi;
        octB[4 + j] = hiS ? hi_lo : hi_hi;
      }
#pragma unroll
      for (int j = 0; j < 8; ++j) {
        float rv = __shfl_xor(octB[j], 32);
        pf0[j] = (bf16)(keep ? octA[j] : rv);
      }
    }
    // ---- butterfly on p[8..15] -> pf1 ----
    {
      float q16[8];
#pragma unroll
      for (int r = 0; r < 8; ++r) q16[r] = __shfl_xor(p[8 + r], 16);
      float octA[8], octB[8];
#pragma unroll
      for (int j = 0; j < 4; ++j) {
        float lo_lo = odd ? q16[j]     : p[8 + j];
        float lo_hi = odd ? q16[4 + j] : p[12 + j];
        float hi_lo = odd ? p[8 + j]   : q16[j];
        float hi_hi = odd ? p[12 + j]  : q16[4 + j];
        octA[j]     = hiS ? lo_hi : lo_lo;
        octA[4 + j] = hiS ? hi_hi : hi_lo;
        octB[j]     = hiS ? lo_lo : lo_hi;
        octB[4 + j] = hiS ? hi_lo : hi_hi;
      }
#pragma unroll
      for (int j = 0; j < 8; ++j) {
        float rv = __shfl_xor(octB[j], 32);
        pf1[j] = (bf16)(keep ? octA[j] : rv);
      }
    }

    // ---- O^T += V^T . P : two mfmas per 16-d block ----
#pragma unroll
    for (int db = 0; db < 4; ++db) {
      bf16x8 vf0 = *reinterpret_cast<const bf16x8*>(&v_s[db * 16 + l16][g4 * 8]);
      bf16x8 vf1 = *reinterpret_cast<const bf16x8*>(&v_s[db * 16 + l16][32 + g4 * 8]);
      oacc[db] = __builtin_amdgcn_mfma_f32_16x16x32_bf16(vf0, pf0, oacc[db], 0, 0, 0);
      oacc[db] = __builtin_amdgcn_mfma_f32_16x16x32_bf16(vf1, pf1, oacc[db], 0, 0, 0);
    }
    __syncthreads();
  }

  // ---- epilogue: transpose via per-wave LDS, coalesced bf16x8 stores ----
  float inv = 1.f / l_r;
#pragma unroll
  for (int db = 0; db < 4; ++db) {
    bf16x4 t4;
#pragma unroll
    for (int r = 0; r < 4; ++r) t4[r] = (bf16)(oacc[db][r] * inv);
    *reinterpret_cast<bf16x4*>(&o_s[wid][l16][db * 16 + g4 * 4]) = t4;
  }
#pragma unroll
  for (int pass = 0; pass < 2; ++pass) {
    int row = (lane >> 3) + pass * 8;
    int c8 = (lane & 7) * 8;
    bf16x8 v = *reinterpret_cast<const bf16x8*>(&o_s[wid][row][c8]);
    *reinterpret_cast<bf16x8*>(Ctx + (size_t)(qrow_w + row) * DIM + h * HD + c8) = v;
  }
}

extern "C" void kernel_launch(void* const* d_in, const int* in_sizes, int n_in,
                              void* d_out, int out_size, void* d_ws, size_t ws_size,
                              hipStream_t stream) {
  const float* query = (const float*)d_in[0];
  const float* key   = (const float*)d_in[1];
  const float* value = (const float*)d_in[2];
  const int*   amask = (const int*)d_in[3];
  const float* Wq = (const float*)d_in[4];
  const float* bq = (const float*)d_in[5];
  const float* Wk = (const float*)d_in[6];
  const float* bk = (const float*)d_in[7];
  const float* Wv = (const float*)d_in[8];
  const float* bv = (const float*)d_in[9];
  const float* Wo = (const float*)d_in[10];
  const float* bo = (const float*)d_in[11];
  const float* ln_g = (const float*)d_in[12];
  const float* ln_b = (const float*)d_in[13];

  char* ws = (char*)d_ws;
  bf16* qln = (bf16*)ws;      ws += (size_t)NB * QLEN * DIM * 2;
  bf16* Qp  = (bf16*)ws;      ws += (size_t)NB * QLEN * DIM * 2;
  bf16* Kp  = (bf16*)ws;      ws += (size_t)NB * KVL * DIM * 2;
  bf16* Vp  = (bf16*)ws;      ws += (size_t)NB * KVL * DIM * 2;
  bf16* Ctx = (bf16*)ws;      ws += (size_t)NB * QLEN * DIM * 2;
  unsigned* mbits = (unsigned*)ws;

  ln_q<<<NB * QLEN / 4, 256, 0, stream>>>(query, ln_g, ln_b, qln);
  pack_mask<<<1024, 256, 0, stream>>>(amask, mbits);

  gemm128<true,  true><<<(NB * QLEN / 128) * 6, 256, 0, stream>>>(qln,   Wq, bq, Qp);
  gemm128<false, true><<<(NB * KVL  / 128) * 6, 256, 0, stream>>>(key,   Wk, bk, Kp);
  gemm128<false, true><<<(NB * KVL  / 128) * 6, 256, 0, stream>>>(value, Wv, bv, Vp);

  attn<<<dim3(NH, QLEN / 64, NB), 256, 0, stream>>>(Qp, Kp, Vp, mbits, Ctx);

  gemm128<true, false><<<(NB * QLEN / 128) * 6, 256, 0, stream>>>(Ctx, Wo, bo, (float*)d_out);
}

// Round 9
// 465.593 us; speedup vs baseline: 1.4601x; 1.0337x over previous
//
#include <hip/hip_runtime.h>
#include <hip/hip_bf16.h>

typedef __bf16 bf16;
typedef bf16 bf16x8 __attribute__((ext_vector_type(8)));
typedef bf16 bf16x4 __attribute__((ext_vector_type(4)));
typedef float f32x4 __attribute__((ext_vector_type(4)));

#define NB 8
#define QLEN 512
#define KVL 4096
#define DIM 768
#define NH 12
#define HD 64

// ---------------- LayerNorm(query) -> bf16 ----------------
__global__ __launch_bounds__(256) void ln_q(const float* __restrict__ x,
    const float* __restrict__ g, const float* __restrict__ beta,
    bf16* __restrict__ out)
{
  int row  = blockIdx.x * 4 + (threadIdx.x >> 6);
  int lane = threadIdx.x & 63;
  const float* rp = x + (size_t)row * DIM;
  f32x4 v[3];
  float s = 0.f, s2 = 0.f;
#pragma unroll
  for (int i = 0; i < 3; ++i) {
    v[i] = *reinterpret_cast<const f32x4*>(rp + (i * 64 + lane) * 4);
#pragma unroll
    for (int j = 0; j < 4; ++j) { s += v[i][j]; s2 += v[i][j] * v[i][j]; }
  }
#pragma unroll
  for (int o = 1; o < 64; o <<= 1) { s += __shfl_xor(s, o); s2 += __shfl_xor(s2, o); }
  float mean = s * (1.f / 768.f);
  float var  = s2 * (1.f / 768.f) - mean * mean;
  float rstd = rsqrtf(var + 1e-5f);
#pragma unroll
  for (int i = 0; i < 3; ++i) {
    int c = (i * 64 + lane) * 4;
    f32x4 gg = *reinterpret_cast<const f32x4*>(g + c);
    f32x4 bb = *reinterpret_cast<const f32x4*>(beta + c);
    bf16x4 o4;
#pragma unroll
    for (int j = 0; j < 4; ++j) o4[j] = (bf16)((v[i][j] - mean) * rstd * gg[j] + bb[j]);
    *reinterpret_cast<bf16x4*>(out + (size_t)row * DIM + c) = o4;
  }
}

// ---------------- mask int32 -> bitmask (bit=1 means masked out) ----------------
__global__ __launch_bounds__(256) void pack_mask(const int* __restrict__ m,
                                                 unsigned* __restrict__ bits)
{
  const int total = NB * QLEN * KVL;
  int stride = gridDim.x * blockDim.x;
  for (int i = blockIdx.x * blockDim.x + threadIdx.x; i < total; i += stride) {
    unsigned long long bal = __ballot(m[i] == 1);
    int lane = threadIdx.x & 63;
    if ((lane & 31) == 0)
      bits[i >> 5] = (unsigned)(bal >> (lane & 32));
  }
}

// ---------------- GEMM: Out[M,768] = A[M,768] @ W[768,768]^T + bias ----------------
// (hardware-verified rounds 4/5/8: f32 W, convert during staging)
template<bool A_IS_BF16, bool OUT_BF16>
__global__ __launch_bounds__(256) void gemm128(const void* __restrict__ Aptr,
    const float* __restrict__ W, const float* __restrict__ bias,
    void* __restrict__ Out)
{
  const int K = 768, N = 768;
  __shared__ __align__(16) bf16 a_s[128][72];
  __shared__ __align__(16) bf16 b_s[128][72];
  int raw = blockIdx.x;
  int nt = (raw >> 3) % 6;
  int mt = ((raw >> 3) / 6) * 8 + (raw & 7);
  int m0 = mt * 128, n0 = nt * 128;
  int tid = threadIdx.x;
  int lane = tid & 63, wid = tid >> 6;
  int l16 = lane & 15, g4 = lane >> 4;
  int wm = wid >> 1, wn = wid & 1;
  f32x4 acc[4][4] = {};

  for (int k0 = 0; k0 < K; k0 += 64) {
#pragma unroll
    for (int i = 0; i < 4; ++i) {
      int oct = tid + i * 256;
      int row = oct >> 3, col = (oct & 7) * 8;
      bf16x8 av;
      if constexpr (A_IS_BF16) {
        av = *reinterpret_cast<const bf16x8*>((const bf16*)Aptr + (size_t)(m0 + row) * K + k0 + col);
      } else {
        const float* ap = (const float*)Aptr + (size_t)(m0 + row) * K + k0 + col;
        f32x4 f0 = *reinterpret_cast<const f32x4*>(ap);
        f32x4 f1 = *reinterpret_cast<const f32x4*>(ap + 4);
#pragma unroll
        for (int j = 0; j < 4; ++j) { av[j] = (bf16)f0[j]; av[4 + j] = (bf16)f1[j]; }
      }
      *reinterpret_cast<bf16x8*>(&a_s[row][col]) = av;

      const float* wp = W + (size_t)(n0 + row) * K + k0 + col;
      f32x4 f0 = *reinterpret_cast<const f32x4*>(wp);
      f32x4 f1 = *reinterpret_cast<const f32x4*>(wp + 4);
      bf16x8 bv;
#pragma unroll
      for (int j = 0; j < 4; ++j) { bv[j] = (bf16)f0[j]; bv[4 + j] = (bf16)f1[j]; }
      *reinterpret_cast<bf16x8*>(&b_s[row][col]) = bv;
    }
    __syncthreads();
#pragma unroll
    for (int kk = 0; kk < 2; ++kk) {
      bf16x8 af[4], bfv[4];
#pragma unroll
      for (int mi = 0; mi < 4; ++mi)
        af[mi] = *reinterpret_cast<const bf16x8*>(&a_s[wm * 64 + mi * 16 + l16][kk * 32 + g4 * 8]);
#pragma unroll
      for (int ni = 0; ni < 4; ++ni)
        bfv[ni] = *reinterpret_cast<const bf16x8*>(&b_s[wn * 64 + ni * 16 + l16][kk * 32 + g4 * 8]);
#pragma unroll
      for (int mi = 0; mi < 4; ++mi)
#pragma unroll
        for (int ni = 0; ni < 4; ++ni)
          acc[mi][ni] = __builtin_amdgcn_mfma_f32_16x16x32_bf16(af[mi], bfv[ni], acc[mi][ni], 0, 0, 0);
    }
    __syncthreads();
  }
#pragma unroll
  for (int mi = 0; mi < 4; ++mi)
#pragma unroll
    for (int ni = 0; ni < 4; ++ni) {
      int col = n0 + wn * 64 + ni * 16 + l16;
      float bv = bias[col];
#pragma unroll
      for (int j = 0; j < 4; ++j) {
        int row = m0 + wm * 64 + mi * 16 + g4 * 4 + j;
        float v = acc[mi][ni][j] + bv;
        if constexpr (OUT_BF16) ((bf16*)Out)[(size_t)row * N + col] = (bf16)v;
        else                    ((float*)Out)[(size_t)row * N + col] = v;
      }
    }
}

// ---------------- fused masked flash attention v6: KVBLK=64 + double-buffer ----------------
// Round-8 verified v5 math and scalar staging patterns, with ONLY the schedule
// changed: double-buffered LDS + register prefetch (issue next tile's global
// loads before compute, write them to the other buffer after compute) -> one
// barrier per 64-kv tile, HBM latency hidden under MFMA+softmax.
__global__ __launch_bounds__(256) void attn(const bf16* __restrict__ Qp,
    const bf16* __restrict__ Kp, const bf16* __restrict__ Vp,
    const unsigned* __restrict__ mbits, bf16* __restrict__ Ctx)
{
  int h = blockIdx.x, qt = blockIdx.y, b = blockIdx.z;
  int tid = threadIdx.x, lane = tid & 63, wid = tid >> 6;
  int g4 = lane >> 4, l16 = lane & 15;
  __shared__ __align__(16) bf16 k_s[2][64][72];
  __shared__ __align__(16) bf16 v_s[2][64][72];
  __shared__ __align__(16) bf16 o_s[4][16][72];

  int qrow_w = b * QLEN + qt * 64 + wid * 16;
  int q = qrow_w + l16;                            // this lane's q row

  bf16x8 qf[2];                                    // pre-scaled by 1/8
#pragma unroll
  for (int kk = 0; kk < 2; ++kk) {
    bf16x8 t = *reinterpret_cast<const bf16x8*>(Qp + (size_t)q * DIM + h * HD + kk * 32 + g4 * 8);
#pragma unroll
    for (int j = 0; j < 8; ++j) qf[kk][j] = (bf16)((float)t[j] * 0.125f);
  }

  const bf16* Kb = Kp + (size_t)b * KVL * DIM + h * HD;
  const bf16* Vb = Vp + (size_t)b * KVL * DIM + h * HD;
  const unsigned* mrow = mbits + (size_t)q * (KVL / 32);

  f32x4 oacc[4] = {};                              // O^T[d=db*16+g4*4+r][q=l16]
  float m_r = -1e30f, l_r = 0.f;

  bool odd = (g4 & 1) != 0;
  bool hiS = (g4 >> 1) != 0;
  bool keep = (g4 == 0) || (g4 == 3);

  int krow = tid >> 3, kcol = (tid & 7) * 8;       // K staging coords
  int vkv = tid & 31, vd0 = (tid >> 5) * 8;        // V staging coords (scalar transpose)

  bf16x8 kreg0, kreg1, vreg0, vreg1;
  unsigned m0w, m1w, m0n, m1n;

  // prologue: tile 0 -> regs -> buf 0
  kreg0 = *reinterpret_cast<const bf16x8*>(Kb + (size_t)krow * DIM + kcol);
  kreg1 = *reinterpret_cast<const bf16x8*>(Kb + (size_t)(krow + 32) * DIM + kcol);
  vreg0 = *reinterpret_cast<const bf16x8*>(Vb + (size_t)vkv * DIM + vd0);
  vreg1 = *reinterpret_cast<const bf16x8*>(Vb + (size_t)(vkv + 32) * DIM + vd0);
  m0w = mrow[0]; m1w = mrow[1];
  *reinterpret_cast<bf16x8*>(&k_s[0][krow][kcol]) = kreg0;
  *reinterpret_cast<bf16x8*>(&k_s[0][krow + 32][kcol]) = kreg1;
#pragma unroll
  for (int j = 0; j < 8; ++j) {
    v_s[0][vd0 + j][vkv] = vreg0[j];
    v_s[0][vd0 + j][vkv + 32] = vreg1[j];
  }
  __syncthreads();

  const int NT = KVL / 64;
  for (int t = 0; t < NT; ++t) {
    int buf = t & 1;
    if (t + 1 < NT) {
      int kv0n = (t + 1) * 64;
      kreg0 = *reinterpret_cast<const bf16x8*>(Kb + (size_t)(kv0n + krow) * DIM + kcol);
      kreg1 = *reinterpret_cast<const bf16x8*>(Kb + (size_t)(kv0n + krow + 32) * DIM + kcol);
      vreg0 = *reinterpret_cast<const bf16x8*>(Vb + (size_t)(kv0n + vkv) * DIM + vd0);
      vreg1 = *reinterpret_cast<const bf16x8*>(Vb + (size_t)(kv0n + vkv + 32) * DIM + vd0);
      m0n = mrow[(t + 1) * 2];
      m1n = mrow[(t + 1) * 2 + 1];
    }

    // ---- S^T = K . Q : 4 kv16-blocks x 2 k-steps ----
    f32x4 sacc[4] = {};
#pragma unroll
    for (int nb = 0; nb < 4; ++nb)
#pragma unroll
      for (int kk = 0; kk < 2; ++kk) {
        bf16x8 kf = *reinterpret_cast<const bf16x8*>(&k_s[buf][nb * 16 + l16][kk * 32 + g4 * 8]);
        sacc[nb] = __builtin_amdgcn_mfma_f32_16x16x32_bf16(kf, qf[kk], sacc[nb], 0, 0, 0);
      }

    // ---- mask: kv = nb*16 + g4*4 + r ----
    float sv[16];
#pragma unroll
    for (int nb = 0; nb < 4; ++nb) {
      unsigned w = (nb < 2) ? m0w : m1w;
#pragma unroll
      for (int r = 0; r < 4; ++r) {
        int bit = (nb & 1) * 16 + g4 * 4 + r;
        sv[nb * 4 + r] = ((w >> bit) & 1u) ? -1e30f : sacc[nb][r];
      }
    }

    // ---- tile max: in-reg tree + 2 shfl ----
    float mx[8];
#pragma unroll
    for (int i = 0; i < 8; ++i) mx[i] = fmaxf(sv[i], sv[i + 8]);
#pragma unroll
    for (int i = 0; i < 4; ++i) mx[i] = fmaxf(mx[i], mx[i + 4]);
    float tm = fmaxf(fmaxf(mx[0], mx[1]), fmaxf(mx[2], mx[3]));
    tm = fmaxf(tm, __shfl_xor(tm, 16));
    tm = fmaxf(tm, __shfl_xor(tm, 32));

    if (!__all(tm <= m_r)) {                       // T13 defer-rescale
      float mnew = fmaxf(m_r, tm);
      float corr = __expf(m_r - mnew);
      m_r = mnew;
      l_r *= corr;
#pragma unroll
      for (int db = 0; db < 4; ++db)
#pragma unroll
        for (int r = 0; r < 4; ++r) oacc[db][r] *= corr;
    }
    float p[16];
#pragma unroll
    for (int i = 0; i < 16; ++i) p[i] = __expf(sv[i] - m_r);
    float sm[8];
#pragma unroll
    for (int i = 0; i < 8; ++i) sm[i] = p[i] + p[i + 8];
#pragma unroll
    for (int i = 0; i < 4; ++i) sm[i] += sm[i + 4];
    float ts = (sm[0] + sm[1]) + (sm[2] + sm[3]);
    ts += __shfl_xor(ts, 16);
    ts += __shfl_xor(ts, 32);
    l_r += ts;

    // ---- butterfly on p[0..7] (round-5/8 verified) -> pf0 ----
    bf16x8 pf0, pf1;
    {
      float q16[8];
#pragma unroll
      for (int r = 0; r < 8; ++r) q16[r] = __shfl_xor(p[r], 16);
      float octA[8], octB[8];
#pragma unroll
      for (int j = 0; j < 4; ++j) {
        float lo_lo = odd ? q16[j]     : p[j];
        float lo_hi = odd ? q16[4 + j] : p[4 + j];
        float hi_lo = odd ? p[j]       : q16[j];
        float hi_hi = odd ? p[4 + j]   : q16[4 + j];
        octA[j]     = hiS ? lo_hi : lo_lo;
        octA[4 + j] = hiS ? hi_hi : hi_lo;
        octB[j]     = hiS ? lo_lo : lo_hi;
        octB[4 + j] = hiS ? hi_lo : hi_hi;
      }
#pragma unroll
      for (int j = 0; j < 8; ++j) {
        float rv = __shfl_xor(octB[j], 32);
        pf0[j] = (bf16)(keep ? octA[j] : rv);
      }
    }
    // ---- butterfly on p[8..15] -> pf1 ----
    {
      float q16[8];
#pragma unroll
      for (int r = 0; r < 8; ++r) q16[r] = __shfl_xor(p[8 + r], 16);
      float octA[8], octB[8];
#pragma unroll
      for (int j = 0; j < 4; ++j) {
        float lo_lo = odd ? q16[j]     : p[8 + j];
        float lo_hi = odd ? q16[4 + j] : p[12 + j];
        float hi_lo = odd ? p[8 + j]   : q16[j];
        float hi_hi = odd ? p[12 + j]  : q16[4 + j];
        octA[j]     = hiS ? lo_hi : lo_lo;
        octA[4 + j] = hiS ? hi_hi : hi_lo;
        octB[j]     = hiS ? lo_lo : lo_hi;
        octB[4 + j] = hiS ? hi_lo : hi_hi;
      }
#pragma unroll
      for (int j = 0; j < 8; ++j) {
        float rv = __shfl_xor(octB[j], 32);
        pf1[j] = (bf16)(keep ? octA[j] : rv);
      }
    }

    // ---- O^T += V^T . P : two mfmas per 16-d block ----
#pragma unroll
    for (int db = 0; db < 4; ++db) {
      bf16x8 vf0 = *reinterpret_cast<const bf16x8*>(&v_s[buf][db * 16 + l16][g4 * 8]);
      bf16x8 vf1 = *reinterpret_cast<const bf16x8*>(&v_s[buf][db * 16 + l16][32 + g4 * 8]);
      oacc[db] = __builtin_amdgcn_mfma_f32_16x16x32_bf16(vf0, pf0, oacc[db], 0, 0, 0);
      oacc[db] = __builtin_amdgcn_mfma_f32_16x16x32_bf16(vf1, pf1, oacc[db], 0, 0, 0);
    }

    // ---- write prefetched tile t+1 into the other buffer ----
    if (t + 1 < NT) {
      int nb2 = buf ^ 1;
      *reinterpret_cast<bf16x8*>(&k_s[nb2][krow][kcol]) = kreg0;
      *reinterpret_cast<bf16x8*>(&k_s[nb2][krow + 32][kcol]) = kreg1;
#pragma unroll
      for (int j = 0; j < 8; ++j) {
        v_s[nb2][vd0 + j][vkv] = vreg0[j];
        v_s[nb2][vd0 + j][vkv + 32] = vreg1[j];
      }
      m0w = m0n; m1w = m1n;
    }
    __syncthreads();
  }

  // ---- epilogue: transpose via per-wave LDS, coalesced bf16x8 stores ----
  float inv = 1.f / l_r;
#pragma unroll
  for (int db = 0; db < 4; ++db) {
    bf16x4 t4;
#pragma unroll
    for (int r = 0; r < 4; ++r) t4[r] = (bf16)(oacc[db][r] * inv);
    *reinterpret_cast<bf16x4*>(&o_s[wid][l16][db * 16 + g4 * 4]) = t4;
  }
#pragma unroll
  for (int pass = 0; pass < 2; ++pass) {
    int row = (lane >> 3) + pass * 8;
    int c8 = (lane & 7) * 8;
    bf16x8 v = *reinterpret_cast<const bf16x8*>(&o_s[wid][row][c8]);
    *reinterpret_cast<bf16x8*>(Ctx + (size_t)(qrow_w + row) * DIM + h * HD + c8) = v;
  }
}

extern "C" void kernel_launch(void* const* d_in, const int* in_sizes, int n_in,
                              void* d_out, int out_size, void* d_ws, size_t ws_size,
                              hipStream_t stream) {
  const float* query = (const float*)d_in[0];
  const float* key   = (const float*)d_in[1];
  const float* value = (const float*)d_in[2];
  const int*   amask = (const int*)d_in[3];
  const float* Wq = (const float*)d_in[4];
  const float* bq = (const float*)d_in[5];
  const float* Wk = (const float*)d_in[6];
  const float* bk = (const float*)d_in[7];
  const float* Wv = (const float*)d_in[8];
  const float* bv = (const float*)d_in[9];
  const float* Wo = (const float*)d_in[10];
  const float* bo = (const float*)d_in[11];
  const float* ln_g = (const float*)d_in[12];
  const float* ln_b = (const float*)d_in[13];

  char* ws = (char*)d_ws;
  bf16* qln = (bf16*)ws;      ws += (size_t)NB * QLEN * DIM * 2;
  bf16* Qp  = (bf16*)ws;      ws += (size_t)NB * QLEN * DIM * 2;
  bf16* Kp  = (bf16*)ws;      ws += (size_t)NB * KVL * DIM * 2;
  bf16* Vp  = (bf16*)ws;      ws += (size_t)NB * KVL * DIM * 2;
  bf16* Ctx = (bf16*)ws;      ws += (size_t)NB * QLEN * DIM * 2;
  unsigned* mbits = (unsigned*)ws;

  ln_q<<<NB * QLEN / 4, 256, 0, stream>>>(query, ln_g, ln_b, qln);
  pack_mask<<<1024, 256, 0, stream>>>(amask, mbits);

  gemm128<true,  true><<<(NB * QLEN / 128) * 6, 256, 0, stream>>>(qln,   Wq, bq, Qp);
  gemm128<false, true><<<(NB * KVL  / 128) * 6, 256, 0, stream>>>(key,   Wk, bk, Kp);
  gemm128<false, true><<<(NB * KVL  / 128) * 6, 256, 0, stream>>>(value, Wv, bv, Vp);

  attn<<<dim3(NH, QLEN / 64, NB), 256, 0, stream>>>(Qp, Kp, Vp, mbits, Ctx);

  gemm128<true, false><<<(NB * QLEN / 128) * 6, 256, 0, stream>>>(Ctx, Wo, bo, (float*)d_out);
}

// Round 10
// 368.418 us; speedup vs baseline: 1.8452x; 1.2638x over previous
//
#include <hip/hip_runtime.h>
#include <hip/hip_bf16.h>

typedef __bf16 bf16;
typedef bf16 bf16x8 __attribute__((ext_vector_type(8)));
typedef bf16 bf16x4 __attribute__((ext_vector_type(4)));
typedef short s16x4 __attribute__((ext_vector_type(4)));
typedef float f32x4 __attribute__((ext_vector_type(4)));

#define NB 8
#define QLEN 512
#define KVL 4096
#define DIM 768
#define NH 12
#define HD 64

// K=16 PV mfma with builtin-name portability (gfx950 may expose either spelling)
#if __has_builtin(__builtin_amdgcn_mfma_f32_16x16x16_bf16)
static __device__ __forceinline__ f32x4 pv16(bf16x4 a, bf16x4 b, f32x4 c) {
  return __builtin_amdgcn_mfma_f32_16x16x16_bf16(a, b, c, 0, 0, 0);
}
#else
static __device__ __forceinline__ f32x4 pv16(bf16x4 a, bf16x4 b, f32x4 c) {
  return __builtin_amdgcn_mfma_f32_16x16x16bf16_1k(
      __builtin_bit_cast(s16x4, a), __builtin_bit_cast(s16x4, b), c, 0, 0, 0);
}
#endif

// ---------------- LayerNorm(query) -> bf16 ----------------
__global__ __launch_bounds__(256) void ln_q(const float* __restrict__ x,
    const float* __restrict__ g, const float* __restrict__ beta,
    bf16* __restrict__ out)
{
  int row  = blockIdx.x * 4 + (threadIdx.x >> 6);
  int lane = threadIdx.x & 63;
  const float* rp = x + (size_t)row * DIM;
  f32x4 v[3];
  float s = 0.f, s2 = 0.f;
#pragma unroll
  for (int i = 0; i < 3; ++i) {
    v[i] = *reinterpret_cast<const f32x4*>(rp + (i * 64 + lane) * 4);
#pragma unroll
    for (int j = 0; j < 4; ++j) { s += v[i][j]; s2 += v[i][j] * v[i][j]; }
  }
#pragma unroll
  for (int o = 1; o < 64; o <<= 1) { s += __shfl_xor(s, o); s2 += __shfl_xor(s2, o); }
  float mean = s * (1.f / 768.f);
  float var  = s2 * (1.f / 768.f) - mean * mean;
  float rstd = rsqrtf(var + 1e-5f);
#pragma unroll
  for (int i = 0; i < 3; ++i) {
    int c = (i * 64 + lane) * 4;
    f32x4 gg = *reinterpret_cast<const f32x4*>(g + c);
    f32x4 bb = *reinterpret_cast<const f32x4*>(beta + c);
    bf16x4 o4;
#pragma unroll
    for (int j = 0; j < 4; ++j) o4[j] = (bf16)((v[i][j] - mean) * rstd * gg[j] + bb[j]);
    *reinterpret_cast<bf16x4*>(out + (size_t)row * DIM + c) = o4;
  }
}

// ---------------- mask int32 -> bitmask (bit=1 means masked out) ----------------
__global__ __launch_bounds__(256) void pack_mask(const int* __restrict__ m,
                                                 unsigned* __restrict__ bits)
{
  const int total = NB * QLEN * KVL;
  int stride = gridDim.x * blockDim.x;
  for (int i = blockIdx.x * blockDim.x + threadIdx.x; i < total; i += stride) {
    unsigned long long bal = __ballot(m[i] == 1);
    int lane = threadIdx.x & 63;
    if ((lane & 31) == 0)
      bits[i >> 5] = (unsigned)(bal >> (lane & 32));
  }
}

// ---------------- W f32 -> bf16 (round-6-proven, 4 matrices via blockIdx.y) ----------------
__global__ __launch_bounds__(256) void conv_w(
    const float* __restrict__ w0, const float* __restrict__ w1,
    const float* __restrict__ w2, const float* __restrict__ w3,
    bf16* __restrict__ o0, bf16* __restrict__ o1,
    bf16* __restrict__ o2, bf16* __restrict__ o3)
{
  int sel = blockIdx.y;
  const float* s = sel == 0 ? w0 : sel == 1 ? w1 : sel == 2 ? w2 : w3;
  bf16* d = sel == 0 ? o0 : sel == 1 ? o1 : sel == 2 ? o2 : o3;
  int i = (blockIdx.x * 256 + threadIdx.x) * 8;
  f32x4 a = *reinterpret_cast<const f32x4*>(s + i);
  f32x4 b = *reinterpret_cast<const f32x4*>(s + i + 4);
  bf16x8 v;
#pragma unroll
  for (int j = 0; j < 4; ++j) { v[j] = (bf16)a[j]; v[4 + j] = (bf16)b[j]; }
  *reinterpret_cast<bf16x8*>(d + i) = v;
}

// ---------------- GEMM: Out[M,768] = A[M,768] @ W[768,768]^T + bias ----------------
// tile 128x128, BK=64, 4 waves 2x2. W pre-converted to bf16 (round-6/7 verified
// value-identical to f32-W staging path).
template<bool A_IS_BF16, bool OUT_BF16>
__global__ __launch_bounds__(256) void gemm128(const void* __restrict__ Aptr,
    const bf16* __restrict__ W, const float* __restrict__ bias,
    void* __restrict__ Out)
{
  const int K = 768, N = 768;
  __shared__ __align__(16) bf16 a_s[128][72];
  __shared__ __align__(16) bf16 b_s[128][72];
  int raw = blockIdx.x;
  int nt = (raw >> 3) % 6;
  int mt = ((raw >> 3) / 6) * 8 + (raw & 7);
  int m0 = mt * 128, n0 = nt * 128;
  int tid = threadIdx.x;
  int lane = tid & 63, wid = tid >> 6;
  int l16 = lane & 15, g4 = lane >> 4;
  int wm = wid >> 1, wn = wid & 1;
  f32x4 acc[4][4] = {};

  for (int k0 = 0; k0 < K; k0 += 64) {
#pragma unroll
    for (int i = 0; i < 4; ++i) {
      int oct = tid + i * 256;
      int row = oct >> 3, col = (oct & 7) * 8;
      bf16x8 av;
      if constexpr (A_IS_BF16) {
        av = *reinterpret_cast<const bf16x8*>((const bf16*)Aptr + (size_t)(m0 + row) * K + k0 + col);
      } else {
        const float* ap = (const float*)Aptr + (size_t)(m0 + row) * K + k0 + col;
        f32x4 f0 = *reinterpret_cast<const f32x4*>(ap);
        f32x4 f1 = *reinterpret_cast<const f32x4*>(ap + 4);
#pragma unroll
        for (int j = 0; j < 4; ++j) { av[j] = (bf16)f0[j]; av[4 + j] = (bf16)f1[j]; }
      }
      *reinterpret_cast<bf16x8*>(&a_s[row][col]) = av;

      *reinterpret_cast<bf16x8*>(&b_s[row][col]) =
          *reinterpret_cast<const bf16x8*>(W + (size_t)(n0 + row) * K + k0 + col);
    }
    __syncthreads();
#pragma unroll
    for (int kk = 0; kk < 2; ++kk) {
      bf16x8 af[4], bfv[4];
#pragma unroll
      for (int mi = 0; mi < 4; ++mi)
        af[mi] = *reinterpret_cast<const bf16x8*>(&a_s[wm * 64 + mi * 16 + l16][kk * 32 + g4 * 8]);
#pragma unroll
      for (int ni = 0; ni < 4; ++ni)
        bfv[ni] = *reinterpret_cast<const bf16x8*>(&b_s[wn * 64 + ni * 16 + l16][kk * 32 + g4 * 8]);
#pragma unroll
      for (int mi = 0; mi < 4; ++mi)
#pragma unroll
        for (int ni = 0; ni < 4; ++ni)
          acc[mi][ni] = __builtin_amdgcn_mfma_f32_16x16x32_bf16(af[mi], bfv[ni], acc[mi][ni], 0, 0, 0);
    }
    __syncthreads();
  }
#pragma unroll
  for (int mi = 0; mi < 4; ++mi)
#pragma unroll
    for (int ni = 0; ni < 4; ++ni) {
      int col = n0 + wn * 64 + ni * 16 + l16;
      float bv = bias[col];
#pragma unroll
      for (int j = 0; j < 4; ++j) {
        int row = m0 + wm * 64 + mi * 16 + g4 * 4 + j;
        float v = acc[mi][ni][j] + bv;
        if constexpr (OUT_BF16) ((bf16*)Out)[(size_t)row * N + col] = (bf16)v;
        else                    ((float*)Out)[(size_t)row * N + col] = v;
      }
    }
}

// ---------------- fused masked flash attention v7 ----------------
// v6 (verified) with PV switched to direct 16x16x16 mfma: lane (l16,g4) already
// holds P[q=l16][kv=nb*16+g4*4+r], which IS the K=16 B-frag layout -> the whole
// butterfly (32 shfl + ~48 sel per tile) is deleted.
__global__ __launch_bounds__(256) void attn(const bf16* __restrict__ Qp,
    const bf16* __restrict__ Kp, const bf16* __restrict__ Vp,
    const unsigned* __restrict__ mbits, bf16* __restrict__ Ctx)
{
  int h = blockIdx.x, qt = blockIdx.y, b = blockIdx.z;
  int tid = threadIdx.x, lane = tid & 63, wid = tid >> 6;
  int g4 = lane >> 4, l16 = lane & 15;
  __shared__ __align__(16) bf16 k_s[2][64][72];
  __shared__ __align__(16) bf16 v_s[2][64][72];
  __shared__ __align__(16) bf16 o_s[4][16][72];

  int qrow_w = b * QLEN + qt * 64 + wid * 16;
  int q = qrow_w + l16;                            // this lane's q row

  bf16x8 qf[2];                                    // pre-scaled by 1/8
#pragma unroll
  for (int kk = 0; kk < 2; ++kk) {
    bf16x8 t = *reinterpret_cast<const bf16x8*>(Qp + (size_t)q * DIM + h * HD + kk * 32 + g4 * 8);
#pragma unroll
    for (int j = 0; j < 8; ++j) qf[kk][j] = (bf16)((float)t[j] * 0.125f);
  }

  const bf16* Kb = Kp + (size_t)b * KVL * DIM + h * HD;
  const bf16* Vb = Vp + (size_t)b * KVL * DIM + h * HD;
  const unsigned* mrow = mbits + (size_t)q * (KVL / 32);

  f32x4 oacc[4] = {};                              // O^T[d=db*16+g4*4+r][q=l16]
  float m_r = -1e30f, l_r = 0.f;

  int krow = tid >> 3, kcol = (tid & 7) * 8;       // K staging coords
  int vkv = tid & 31, vd0 = (tid >> 5) * 8;        // V staging coords (scalar transpose)

  bf16x8 kreg0, kreg1, vreg0, vreg1;
  unsigned m0w, m1w, m0n, m1n;

  // prologue: tile 0 -> regs -> buf 0
  kreg0 = *reinterpret_cast<const bf16x8*>(Kb + (size_t)krow * DIM + kcol);
  kreg1 = *reinterpret_cast<const bf16x8*>(Kb + (size_t)(krow + 32) * DIM + kcol);
  vreg0 = *reinterpret_cast<const bf16x8*>(Vb + (size_t)vkv * DIM + vd0);
  vreg1 = *reinterpret_cast<const bf16x8*>(Vb + (size_t)(vkv + 32) * DIM + vd0);
  m0w = mrow[0]; m1w = mrow[1];
  *reinterpret_cast<bf16x8*>(&k_s[0][krow][kcol]) = kreg0;
  *reinterpret_cast<bf16x8*>(&k_s[0][krow + 32][kcol]) = kreg1;
#pragma unroll
  for (int j = 0; j < 8; ++j) {
    v_s[0][vd0 + j][vkv] = vreg0[j];
    v_s[0][vd0 + j][vkv + 32] = vreg1[j];
  }
  __syncthreads();

  const int NT = KVL / 64;
  for (int t = 0; t < NT; ++t) {
    int buf = t & 1;
    if (t + 1 < NT) {
      int kv0n = (t + 1) * 64;
      kreg0 = *reinterpret_cast<const bf16x8*>(Kb + (size_t)(kv0n + krow) * DIM + kcol);
      kreg1 = *reinterpret_cast<const bf16x8*>(Kb + (size_t)(kv0n + krow + 32) * DIM + kcol);
      vreg0 = *reinterpret_cast<const bf16x8*>(Vb + (size_t)(kv0n + vkv) * DIM + vd0);
      vreg1 = *reinterpret_cast<const bf16x8*>(Vb + (size_t)(kv0n + vkv + 32) * DIM + vd0);
      m0n = mrow[(t + 1) * 2];
      m1n = mrow[(t + 1) * 2 + 1];
    }

    // ---- S^T = K . Q : 4 kv16-blocks x 2 k-steps ----
    f32x4 sacc[4] = {};
#pragma unroll
    for (int nb = 0; nb < 4; ++nb)
#pragma unroll
      for (int kk = 0; kk < 2; ++kk) {
        bf16x8 kf = *reinterpret_cast<const bf16x8*>(&k_s[buf][nb * 16 + l16][kk * 32 + g4 * 8]);
        sacc[nb] = __builtin_amdgcn_mfma_f32_16x16x32_bf16(kf, qf[kk], sacc[nb], 0, 0, 0);
      }

    // ---- mask: kv = nb*16 + g4*4 + r ----
    float sv[16];
#pragma unroll
    for (int nb = 0; nb < 4; ++nb) {
      unsigned w = (nb < 2) ? m0w : m1w;
#pragma unroll
      for (int r = 0; r < 4; ++r) {
        int bit = (nb & 1) * 16 + g4 * 4 + r;
        sv[nb * 4 + r] = ((w >> bit) & 1u) ? -1e30f : sacc[nb][r];
      }
    }

    // ---- tile max: in-reg tree + 2 shfl ----
    float mx[8];
#pragma unroll
    for (int i = 0; i < 8; ++i) mx[i] = fmaxf(sv[i], sv[i + 8]);
#pragma unroll
    for (int i = 0; i < 4; ++i) mx[i] = fmaxf(mx[i], mx[i + 4]);
    float tm = fmaxf(fmaxf(mx[0], mx[1]), fmaxf(mx[2], mx[3]));
    tm = fmaxf(tm, __shfl_xor(tm, 16));
    tm = fmaxf(tm, __shfl_xor(tm, 32));

    if (!__all(tm <= m_r)) {                       // T13 defer-rescale
      float mnew = fmaxf(m_r, tm);
      float corr = __expf(m_r - mnew);
      m_r = mnew;
      l_r *= corr;
#pragma unroll
      for (int db = 0; db < 4; ++db)
#pragma unroll
        for (int r = 0; r < 4; ++r) oacc[db][r] *= corr;
    }
    float p[16];
#pragma unroll
    for (int i = 0; i < 16; ++i) p[i] = __expf(sv[i] - m_r);
    float sm[8];
#pragma unroll
    for (int i = 0; i < 8; ++i) sm[i] = p[i] + p[i + 8];
#pragma unroll
    for (int i = 0; i < 4; ++i) sm[i] += sm[i + 4];
    float ts = (sm[0] + sm[1]) + (sm[2] + sm[3]);
    ts += __shfl_xor(ts, 16);
    ts += __shfl_xor(ts, 32);
    l_r += ts;

    // ---- P -> bf16 B-frags for K=16 mfma (layout is already correct, no shuffle) ----
    bf16x4 pq[4];
#pragma unroll
    for (int nb = 0; nb < 4; ++nb)
#pragma unroll
      for (int j = 0; j < 4; ++j) pq[nb][j] = (bf16)p[nb * 4 + j];

    // ---- O^T += V^T . P : 4 nb-slices x 4 d-blocks of 16x16x16 ----
#pragma unroll
    for (int db = 0; db < 4; ++db)
#pragma unroll
      for (int nb = 0; nb < 4; ++nb) {
        bf16x4 vf = *reinterpret_cast<const bf16x4*>(&v_s[buf][db * 16 + l16][nb * 16 + g4 * 4]);
        oacc[db] = pv16(vf, pq[nb], oacc[db]);
      }

    // ---- write prefetched tile t+1 into the other buffer ----
    if (t + 1 < NT) {
      int nb2 = buf ^ 1;
      *reinterpret_cast<bf16x8*>(&k_s[nb2][krow][kcol]) = kreg0;
      *reinterpret_cast<bf16x8*>(&k_s[nb2][krow + 32][kcol]) = kreg1;
#pragma unroll
      for (int j = 0; j < 8; ++j) {
        v_s[nb2][vd0 + j][vkv] = vreg0[j];
        v_s[nb2][vd0 + j][vkv + 32] = vreg1[j];
      }
      m0w = m0n; m1w = m1n;
    }
    __syncthreads();
  }

  // ---- epilogue: transpose via per-wave LDS, coalesced bf16x8 stores ----
  float inv = 1.f / l_r;
#pragma unroll
  for (int db = 0; db < 4; ++db) {
    bf16x4 t4;
#pragma unroll
    for (int r = 0; r < 4; ++r) t4[r] = (bf16)(oacc[db][r] * inv);
    *reinterpret_cast<bf16x4*>(&o_s[wid][l16][db * 16 + g4 * 4]) = t4;
  }
#pragma unroll
  for (int pass = 0; pass < 2; ++pass) {
    int row = (lane >> 3) + pass * 8;
    int c8 = (lane & 7) * 8;
    bf16x8 v = *reinterpret_cast<const bf16x8*>(&o_s[wid][row][c8]);
    *reinterpret_cast<bf16x8*>(Ctx + (size_t)(qrow_w + row) * DIM + h * HD + c8) = v;
  }
}

extern "C" void kernel_launch(void* const* d_in, const int* in_sizes, int n_in,
                              void* d_out, int out_size, void* d_ws, size_t ws_size,
                              hipStream_t stream) {
  const float* query = (const float*)d_in[0];
  const float* key   = (const float*)d_in[1];
  const float* value = (const float*)d_in[2];
  const int*   amask = (const int*)d_in[3];
  const float* Wq = (const float*)d_in[4];
  const float* bq = (const float*)d_in[5];
  const float* Wk = (const float*)d_in[6];
  const float* bk = (const float*)d_in[7];
  const float* Wv = (const float*)d_in[8];
  const float* bv = (const float*)d_in[9];
  const float* Wo = (const float*)d_in[10];
  const float* bo = (const float*)d_in[11];
  const float* ln_g = (const float*)d_in[12];
  const float* ln_b = (const float*)d_in[13];

  char* ws = (char*)d_ws;
  bf16* qln = (bf16*)ws;      ws += (size_t)NB * QLEN * DIM * 2;
  bf16* Qp  = (bf16*)ws;      ws += (size_t)NB * QLEN * DIM * 2;
  bf16* Kp  = (bf16*)ws;      ws += (size_t)NB * KVL * DIM * 2;
  bf16* Vp  = (bf16*)ws;      ws += (size_t)NB * KVL * DIM * 2;
  bf16* Ctx = (bf16*)ws;      ws += (size_t)NB * QLEN * DIM * 2;
  unsigned* mbits = (unsigned*)ws; ws += (size_t)NB * QLEN * (KVL / 32) * 4;
  bf16* Wqb = (bf16*)ws;      ws += (size_t)DIM * DIM * 2;
  bf16* Wkb = (bf16*)ws;      ws += (size_t)DIM * DIM * 2;
  bf16* Wvb = (bf16*)ws;      ws += (size_t)DIM * DIM * 2;
  bf16* Wob = (bf16*)ws;

  ln_q<<<NB * QLEN / 4, 256, 0, stream>>>(query, ln_g, ln_b, qln);
  pack_mask<<<1024, 256, 0, stream>>>(amask, mbits);
  conv_w<<<dim3(DIM * DIM / (256 * 8), 4), 256, 0, stream>>>(Wq, Wk, Wv, Wo, Wqb, Wkb, Wvb, Wob);

  gemm128<true,  true><<<(NB * QLEN / 128) * 6, 256, 0, stream>>>(qln,   Wqb, bq, Qp);
  gemm128<false, true><<<(NB * KVL  / 128) * 6, 256, 0, stream>>>(key,   Wkb, bk, Kp);
  gemm128<false, true><<<(NB * KVL  / 128) * 6, 256, 0, stream>>>(value, Wvb, bv, Vp);

  attn<<<dim3(NH, QLEN / 64, NB), 256, 0, stream>>>(Qp, Kp, Vp, mbits, Ctx);

  gemm128<true, false><<<(NB * QLEN / 128) * 6, 256, 0, stream>>>(Ctx, Wob, bo, (float*)d_out);
}

// Round 11
// 359.128 us; speedup vs baseline: 1.8930x; 1.0259x over previous
//
#include <hip/hip_runtime.h>
#include <hip/hip_bf16.h>

typedef __bf16 bf16;
typedef bf16 bf16x8 __attribute__((ext_vector_type(8)));
typedef bf16 bf16x4 __attribute__((ext_vector_type(4)));
typedef short s16x4 __attribute__((ext_vector_type(4)));
typedef float f32x4 __attribute__((ext_vector_type(4)));

#define NB 8
#define QLEN 512
#define KVL 4096
#define DIM 768
#define NH 12
#define HD 64

// K=16 PV mfma with builtin-name portability (gfx950 may expose either spelling)
#if __has_builtin(__builtin_amdgcn_mfma_f32_16x16x16_bf16)
static __device__ __forceinline__ f32x4 pv16(bf16x4 a, bf16x4 b, f32x4 c) {
  return __builtin_amdgcn_mfma_f32_16x16x16_bf16(a, b, c, 0, 0, 0);
}
#else
static __device__ __forceinline__ f32x4 pv16(bf16x4 a, bf16x4 b, f32x4 c) {
  return __builtin_amdgcn_mfma_f32_16x16x16bf16_1k(
      __builtin_bit_cast(s16x4, a), __builtin_bit_cast(s16x4, b), c, 0, 0, 0);
}
#endif

// ---------------- LayerNorm(query) -> bf16 ----------------
__global__ __launch_bounds__(256) void ln_q(const float* __restrict__ x,
    const float* __restrict__ g, const float* __restrict__ beta,
    bf16* __restrict__ out)
{
  int row  = blockIdx.x * 4 + (threadIdx.x >> 6);
  int lane = threadIdx.x & 63;
  const float* rp = x + (size_t)row * DIM;
  f32x4 v[3];
  float s = 0.f, s2 = 0.f;
#pragma unroll
  for (int i = 0; i < 3; ++i) {
    v[i] = *reinterpret_cast<const f32x4*>(rp + (i * 64 + lane) * 4);
#pragma unroll
    for (int j = 0; j < 4; ++j) { s += v[i][j]; s2 += v[i][j] * v[i][j]; }
  }
#pragma unroll
  for (int o = 1; o < 64; o <<= 1) { s += __shfl_xor(s, o); s2 += __shfl_xor(s2, o); }
  float mean = s * (1.f / 768.f);
  float var  = s2 * (1.f / 768.f) - mean * mean;
  float rstd = rsqrtf(var + 1e-5f);
#pragma unroll
  for (int i = 0; i < 3; ++i) {
    int c = (i * 64 + lane) * 4;
    f32x4 gg = *reinterpret_cast<const f32x4*>(g + c);
    f32x4 bb = *reinterpret_cast<const f32x4*>(beta + c);
    bf16x4 o4;
#pragma unroll
    for (int j = 0; j < 4; ++j) o4[j] = (bf16)((v[i][j] - mean) * rstd * gg[j] + bb[j]);
    *reinterpret_cast<bf16x4*>(out + (size_t)row * DIM + c) = o4;
  }
}

// ---------------- mask int32 -> bitmask (bit=1 means masked out) ----------------
__global__ __launch_bounds__(256) void pack_mask(const int* __restrict__ m,
                                                 unsigned* __restrict__ bits)
{
  const int total = NB * QLEN * KVL;
  int stride = gridDim.x * blockDim.x;
  for (int i = blockIdx.x * blockDim.x + threadIdx.x; i < total; i += stride) {
    unsigned long long bal = __ballot(m[i] == 1);
    int lane = threadIdx.x & 63;
    if ((lane & 31) == 0)
      bits[i >> 5] = (unsigned)(bal >> (lane & 32));
  }
}

// ---------------- W f32 -> bf16 (round-6/10-proven) ----------------
__global__ __launch_bounds__(256) void conv_w(
    const float* __restrict__ w0, const float* __restrict__ w1,
    const float* __restrict__ w2, const float* __restrict__ w3,
    bf16* __restrict__ o0, bf16* __restrict__ o1,
    bf16* __restrict__ o2, bf16* __restrict__ o3)
{
  int sel = blockIdx.y;
  const float* s = sel == 0 ? w0 : sel == 1 ? w1 : sel == 2 ? w2 : w3;
  bf16* d = sel == 0 ? o0 : sel == 1 ? o1 : sel == 2 ? o2 : o3;
  int i = (blockIdx.x * 256 + threadIdx.x) * 8;
  f32x4 a = *reinterpret_cast<const f32x4*>(s + i);
  f32x4 b = *reinterpret_cast<const f32x4*>(s + i + 4);
  bf16x8 v;
#pragma unroll
  for (int j = 0; j < 4; ++j) { v[j] = (bf16)a[j]; v[4 + j] = (bf16)b[j]; }
  *reinterpret_cast<bf16x8*>(d + i) = v;
}

// ---------------- GEMM: Out[M,768] = A[M,768] @ W[768,768]^T + bias ----------------
// (hardware-verified round 10: bf16 W, 128x128 tile, 4 waves 2x2)
template<bool A_IS_BF16, bool OUT_BF16>
__global__ __launch_bounds__(256) void gemm128(const void* __restrict__ Aptr,
    const bf16* __restrict__ W, const float* __restrict__ bias,
    void* __restrict__ Out)
{
  const int K = 768, N = 768;
  __shared__ __align__(16) bf16 a_s[128][72];
  __shared__ __align__(16) bf16 b_s[128][72];
  int raw = blockIdx.x;
  int nt = (raw >> 3) % 6;
  int mt = ((raw >> 3) / 6) * 8 + (raw & 7);
  int m0 = mt * 128, n0 = nt * 128;
  int tid = threadIdx.x;
  int lane = tid & 63, wid = tid >> 6;
  int l16 = lane & 15, g4 = lane >> 4;
  int wm = wid >> 1, wn = wid & 1;
  f32x4 acc[4][4] = {};

  for (int k0 = 0; k0 < K; k0 += 64) {
#pragma unroll
    for (int i = 0; i < 4; ++i) {
      int oct = tid + i * 256;
      int row = oct >> 3, col = (oct & 7) * 8;
      bf16x8 av;
      if constexpr (A_IS_BF16) {
        av = *reinterpret_cast<const bf16x8*>((const bf16*)Aptr + (size_t)(m0 + row) * K + k0 + col);
      } else {
        const float* ap = (const float*)Aptr + (size_t)(m0 + row) * K + k0 + col;
        f32x4 f0 = *reinterpret_cast<const f32x4*>(ap);
        f32x4 f1 = *reinterpret_cast<const f32x4*>(ap + 4);
#pragma unroll
        for (int j = 0; j < 4; ++j) { av[j] = (bf16)f0[j]; av[4 + j] = (bf16)f1[j]; }
      }
      *reinterpret_cast<bf16x8*>(&a_s[row][col]) = av;

      *reinterpret_cast<bf16x8*>(&b_s[row][col]) =
          *reinterpret_cast<const bf16x8*>(W + (size_t)(n0 + row) * K + k0 + col);
    }
    __syncthreads();
#pragma unroll
    for (int kk = 0; kk < 2; ++kk) {
      bf16x8 af[4], bfv[4];
#pragma unroll
      for (int mi = 0; mi < 4; ++mi)
        af[mi] = *reinterpret_cast<const bf16x8*>(&a_s[wm * 64 + mi * 16 + l16][kk * 32 + g4 * 8]);
#pragma unroll
      for (int ni = 0; ni < 4; ++ni)
        bfv[ni] = *reinterpret_cast<const bf16x8*>(&b_s[wn * 64 + ni * 16 + l16][kk * 32 + g4 * 8]);
#pragma unroll
      for (int mi = 0; mi < 4; ++mi)
#pragma unroll
        for (int ni = 0; ni < 4; ++ni)
          acc[mi][ni] = __builtin_amdgcn_mfma_f32_16x16x32_bf16(af[mi], bfv[ni], acc[mi][ni], 0, 0, 0);
    }
    __syncthreads();
  }
#pragma unroll
  for (int mi = 0; mi < 4; ++mi)
#pragma unroll
    for (int ni = 0; ni < 4; ++ni) {
      int col = n0 + wn * 64 + ni * 16 + l16;
      float bv = bias[col];
#pragma unroll
      for (int j = 0; j < 4; ++j) {
        int row = m0 + wm * 64 + mi * 16 + g4 * 4 + j;
        float v = acc[mi][ni][j] + bv;
        if constexpr (OUT_BF16) ((bf16*)Out)[(size_t)row * N + col] = (bf16)v;
        else                    ((float*)Out)[(size_t)row * N + col] = v;
      }
    }
}

// ---------------- fused masked flash attention v8 ----------------
// v7 (verified) with: (1) epilogue transpose buffer aliased onto k_s (dead after
// the final barrier) -> LDS 46080 -> 36864 B -> 4 blocks/CU (16 waves, +33%
// latency hiding for the serial softmax chain); (2) max tree as 3-input chains
// for v_max3 fusion (15 -> 8 ops).
__global__ __launch_bounds__(256, 4) void attn(const bf16* __restrict__ Qp,
    const bf16* __restrict__ Kp, const bf16* __restrict__ Vp,
    const unsigned* __restrict__ mbits, bf16* __restrict__ Ctx)
{
  int h = blockIdx.x, qt = blockIdx.y, b = blockIdx.z;
  int tid = threadIdx.x, lane = tid & 63, wid = tid >> 6;
  int g4 = lane >> 4, l16 = lane & 15;
  __shared__ __align__(16) bf16 k_s[2][64][72];
  __shared__ __align__(16) bf16 v_s[2][64][72];

  int qrow_w = b * QLEN + qt * 64 + wid * 16;
  int q = qrow_w + l16;                            // this lane's q row

  bf16x8 qf[2];                                    // pre-scaled by 1/8
#pragma unroll
  for (int kk = 0; kk < 2; ++kk) {
    bf16x8 t = *reinterpret_cast<const bf16x8*>(Qp + (size_t)q * DIM + h * HD + kk * 32 + g4 * 8);
#pragma unroll
    for (int j = 0; j < 8; ++j) qf[kk][j] = (bf16)((float)t[j] * 0.125f);
  }

  const bf16* Kb = Kp + (size_t)b * KVL * DIM + h * HD;
  const bf16* Vb = Vp + (size_t)b * KVL * DIM + h * HD;
  const unsigned* mrow = mbits + (size_t)q * (KVL / 32);

  f32x4 oacc[4] = {};                              // O^T[d=db*16+g4*4+r][q=l16]
  float m_r = -1e30f, l_r = 0.f;

  int krow = tid >> 3, kcol = (tid & 7) * 8;       // K staging coords
  int vkv = tid & 31, vd0 = (tid >> 5) * 8;        // V staging coords (scalar transpose)

  bf16x8 kreg0, kreg1, vreg0, vreg1;
  unsigned m0w, m1w, m0n, m1n;

  // prologue: tile 0 -> regs -> buf 0
  kreg0 = *reinterpret_cast<const bf16x8*>(Kb + (size_t)krow * DIM + kcol);
  kreg1 = *reinterpret_cast<const bf16x8*>(Kb + (size_t)(krow + 32) * DIM + kcol);
  vreg0 = *reinterpret_cast<const bf16x8*>(Vb + (size_t)vkv * DIM + vd0);
  vreg1 = *reinterpret_cast<const bf16x8*>(Vb + (size_t)(vkv + 32) * DIM + vd0);
  m0w = mrow[0]; m1w = mrow[1];
  *reinterpret_cast<bf16x8*>(&k_s[0][krow][kcol]) = kreg0;
  *reinterpret_cast<bf16x8*>(&k_s[0][krow + 32][kcol]) = kreg1;
#pragma unroll
  for (int j = 0; j < 8; ++j) {
    v_s[0][vd0 + j][vkv] = vreg0[j];
    v_s[0][vd0 + j][vkv + 32] = vreg1[j];
  }
  __syncthreads();

  const int NT = KVL / 64;
  for (int t = 0; t < NT; ++t) {
    int buf = t & 1;
    if (t + 1 < NT) {
      int kv0n = (t + 1) * 64;
      kreg0 = *reinterpret_cast<const bf16x8*>(Kb + (size_t)(kv0n + krow) * DIM + kcol);
      kreg1 = *reinterpret_cast<const bf16x8*>(Kb + (size_t)(kv0n + krow + 32) * DIM + kcol);
      vreg0 = *reinterpret_cast<const bf16x8*>(Vb + (size_t)(kv0n + vkv) * DIM + vd0);
      vreg1 = *reinterpret_cast<const bf16x8*>(Vb + (size_t)(kv0n + vkv + 32) * DIM + vd0);
      m0n = mrow[(t + 1) * 2];
      m1n = mrow[(t + 1) * 2 + 1];
    }

    // ---- S^T = K . Q : 4 kv16-blocks x 2 k-steps ----
    f32x4 sacc[4] = {};
#pragma unroll
    for (int nb = 0; nb < 4; ++nb)
#pragma unroll
      for (int kk = 0; kk < 2; ++kk) {
        bf16x8 kf = *reinterpret_cast<const bf16x8*>(&k_s[buf][nb * 16 + l16][kk * 32 + g4 * 8]);
        sacc[nb] = __builtin_amdgcn_mfma_f32_16x16x32_bf16(kf, qf[kk], sacc[nb], 0, 0, 0);
      }

    // ---- mask: kv = nb*16 + g4*4 + r ----
    float sv[16];
#pragma unroll
    for (int nb = 0; nb < 4; ++nb) {
      unsigned w = (nb < 2) ? m0w : m1w;
#pragma unroll
      for (int r = 0; r < 4; ++r) {
        int bit = (nb & 1) * 16 + g4 * 4 + r;
        sv[nb * 4 + r] = ((w >> bit) & 1u) ? -1e30f : sacc[nb][r];
      }
    }

    // ---- tile max: 3-input chains (v_max3 fusion) + 2 shfl ----
    float a0 = fmaxf(fmaxf(sv[0], sv[1]), sv[2]);
    float a1 = fmaxf(fmaxf(sv[3], sv[4]), sv[5]);
    float a2 = fmaxf(fmaxf(sv[6], sv[7]), sv[8]);
    float a3 = fmaxf(fmaxf(sv[9], sv[10]), sv[11]);
    float a4 = fmaxf(fmaxf(sv[12], sv[13]), sv[14]);
    float b0 = fmaxf(fmaxf(a0, a1), sv[15]);
    float b1 = fmaxf(fmaxf(a2, a3), a4);
    float tm = fmaxf(b0, b1);
    tm = fmaxf(tm, __shfl_xor(tm, 16));
    tm = fmaxf(tm, __shfl_xor(tm, 32));

    if (!__all(tm <= m_r)) {                       // T13 defer-rescale
      float mnew = fmaxf(m_r, tm);
      float corr = __expf(m_r - mnew);
      m_r = mnew;
      l_r *= corr;
#pragma unroll
      for (int db = 0; db < 4; ++db)
#pragma unroll
        for (int r = 0; r < 4; ++r) oacc[db][r] *= corr;
    }
    float p[16];
#pragma unroll
    for (int i = 0; i < 16; ++i) p[i] = __expf(sv[i] - m_r);
    float sm[8];
#pragma unroll
    for (int i = 0; i < 8; ++i) sm[i] = p[i] + p[i + 8];
#pragma unroll
    for (int i = 0; i < 4; ++i) sm[i] += sm[i + 4];
    float ts = (sm[0] + sm[1]) + (sm[2] + sm[3]);
    ts += __shfl_xor(ts, 16);
    ts += __shfl_xor(ts, 32);
    l_r += ts;

    // ---- P -> bf16 B-frags for K=16 mfma (layout already correct) ----
    bf16x4 pq[4];
#pragma unroll
    for (int nb = 0; nb < 4; ++nb)
#pragma unroll
      for (int j = 0; j < 4; ++j) pq[nb][j] = (bf16)p[nb * 4 + j];

    // ---- O^T += V^T . P : 4 nb-slices x 4 d-blocks of 16x16x16 ----
#pragma unroll
    for (int db = 0; db < 4; ++db)
#pragma unroll
      for (int nb = 0; nb < 4; ++nb) {
        bf16x4 vf = *reinterpret_cast<const bf16x4*>(&v_s[buf][db * 16 + l16][nb * 16 + g4 * 4]);
        oacc[db] = pv16(vf, pq[nb], oacc[db]);
      }

    // ---- write prefetched tile t+1 into the other buffer ----
    if (t + 1 < NT) {
      int nb2 = buf ^ 1;
      *reinterpret_cast<bf16x8*>(&k_s[nb2][krow][kcol]) = kreg0;
      *reinterpret_cast<bf16x8*>(&k_s[nb2][krow + 32][kcol]) = kreg1;
#pragma unroll
      for (int j = 0; j < 8; ++j) {
        v_s[nb2][vd0 + j][vkv] = vreg0[j];
        v_s[nb2][vd0 + j][vkv + 32] = vreg1[j];
      }
      m0w = m0n; m1w = m1n;
    }
    __syncthreads();
  }

  // ---- epilogue: transpose via LDS aliased onto k_s (dead after final barrier;
  // all waves passed that barrier, each wave touches only its own 16x72 chunk) ----
  bf16* o_base = &k_s[0][0][0] + (size_t)wid * 16 * 72;
  float inv = 1.f / l_r;
#pragma unroll
  for (int db = 0; db < 4; ++db) {
    bf16x4 t4;
#pragma unroll
    for (int r = 0; r < 4; ++r) t4[r] = (bf16)(oacc[db][r] * inv);
    *reinterpret_cast<bf16x4*>(o_base + l16 * 72 + db * 16 + g4 * 4) = t4;
  }
#pragma unroll
  for (int pass = 0; pass < 2; ++pass) {
    int row = (lane >> 3) + pass * 8;
    int c8 = (lane & 7) * 8;
    bf16x8 v = *reinterpret_cast<const bf16x8*>(o_base + row * 72 + c8);
    *reinterpret_cast<bf16x8*>(Ctx + (size_t)(qrow_w + row) * DIM + h * HD + c8) = v;
  }
}

extern "C" void kernel_launch(void* const* d_in, const int* in_sizes, int n_in,
                              void* d_out, int out_size, void* d_ws, size_t ws_size,
                              hipStream_t stream) {
  const float* query = (const float*)d_in[0];
  const float* key   = (const float*)d_in[1];
  const float* value = (const float*)d_in[2];
  const int*   amask = (const int*)d_in[3];
  const float* Wq = (const float*)d_in[4];
  const float* bq = (const float*)d_in[5];
  const float* Wk = (const float*)d_in[6];
  const float* bk = (const float*)d_in[7];
  const float* Wv = (const float*)d_in[8];
  const float* bv = (const float*)d_in[9];
  const float* Wo = (const float*)d_in[10];
  const float* bo = (const float*)d_in[11];
  const float* ln_g = (const float*)d_in[12];
  const float* ln_b = (const float*)d_in[13];

  char* ws = (char*)d_ws;
  bf16* qln = (bf16*)ws;      ws += (size_t)NB * QLEN * DIM * 2;
  bf16* Qp  = (bf16*)ws;      ws += (size_t)NB * QLEN * DIM * 2;
  bf16* Kp  = (bf16*)ws;      ws += (size_t)NB * KVL * DIM * 2;
  bf16* Vp  = (bf16*)ws;      ws += (size_t)NB * KVL * DIM * 2;
  bf16* Ctx = (bf16*)ws;      ws += (size_t)NB * QLEN * DIM * 2;
  unsigned* mbits = (unsigned*)ws; ws += (size_t)NB * QLEN * (KVL / 32) * 4;
  bf16* Wqb = (bf16*)ws;      ws += (size_t)DIM * DIM * 2;
  bf16* Wkb = (bf16*)ws;      ws += (size_t)DIM * DIM * 2;
  bf16* Wvb = (bf16*)ws;      ws += (size_t)DIM * DIM * 2;
  bf16* Wob = (bf16*)ws;

  ln_q<<<NB * QLEN / 4, 256, 0, stream>>>(query, ln_g, ln_b, qln);
  pack_mask<<<1024, 256, 0, stream>>>(amask, mbits);
  conv_w<<<dim3(DIM * DIM / (256 * 8), 4), 256, 0, stream>>>(Wq, Wk, Wv, Wo, Wqb, Wkb, Wvb, Wob);

  gemm128<true,  true><<<(NB * QLEN / 128) * 6, 256, 0, stream>>>(qln,   Wqb, bq, Qp);
  gemm128<false, true><<<(NB * KVL  / 128) * 6, 256, 0, stream>>>(key,   Wkb, bk, Kp);
  gemm128<false, true><<<(NB * KVL  / 128) * 6, 256, 0, stream>>>(value, Wvb, bv, Vp);

  attn<<<dim3(NH, QLEN / 64, NB), 256, 0, stream>>>(Qp, Kp, Vp, mbits, Ctx);

  gemm128<true, false><<<(NB * QLEN / 128) * 6, 256, 0, stream>>>(Ctx, Wob, bo, (float*)d_out);
}